// Round 2
// baseline (4710.387 us; speedup 1.0000x reference)
//
#include <hip/hip_runtime.h>
#include <cstdint>
#include <cstddef>

#define WAYS  100
#define SHOTS 5
#define NQ    10000
#define DIM   2048
#define KSEL  512

#define BQ 128
#define BW 64
#define BK 32
#define PADQ 4
#define PADW 4

struct Ctrl {
  double klsum[2];   // [0]=dctl, [1]=resl
  double wsum[2];
  float  w0[2];
  int    R, Dn;
  unsigned int T[8];
  int rem[8];
  int kk[8];
};

__device__ __forceinline__ unsigned int monokey(float f){
  unsigned int b = __float_as_uint(f);
  return (b & 0x80000000u) ? ~b : (b | 0x80000000u);
}

// ---- prototypes: mean over shots, then row l2-norm -------------------------
__global__ void proto_kernel(const float* __restrict__ xs, const float* __restrict__ dsh,
                             float* __restrict__ protoX, float* __restrict__ protoD){
  int b = blockIdx.x;
  const float* src = (b < WAYS) ? xs : dsh;
  float* dst = (b < WAYS) ? protoX : protoD;
  int w = (b < WAYS) ? b : b - WAYS;
  __shared__ float meanv[DIM];
  __shared__ float red[256];
  float loc = 0.f;
  for (int d = threadIdx.x; d < DIM; d += 256){
    float s = 0.f;
    for (int sh = 0; sh < SHOTS; sh++) s += src[((size_t)w*SHOTS + sh)*DIM + d];
    float m = s / (float)SHOTS;
    meanv[d] = m;
    loc += m*m;
  }
  red[threadIdx.x] = loc; __syncthreads();
  for (int st = 128; st > 0; st >>= 1){
    if (threadIdx.x < st) red[threadIdx.x] += red[threadIdx.x + st];
    __syncthreads();
  }
  float inv = 1.0f / fmaxf(sqrtf(red[0]), 1e-12f);
  for (int d = threadIdx.x; d < DIM; d += 256)
    dst[(size_t)w*DIM + d] = meanv[d] * inv;
}

// ---- per-query inverse L2 norm ---------------------------------------------
__global__ void invnorm_kernel(const float* __restrict__ xq, const float* __restrict__ dq,
                               float* __restrict__ invnX, float* __restrict__ invnD){
  int r = blockIdx.x;                       // 0..2*NQ-1
  const float* src = (r < NQ) ? xq : dq;
  float* dst = (r < NQ) ? invnX : invnD;
  int q = (r < NQ) ? r : r - NQ;
  const float4* row = (const float4*)(src + (size_t)q*DIM);
  float s = 0.f;
  for (int i = threadIdx.x; i < DIM/4; i += 64){
    float4 v = row[i];
    s += v.x*v.x + v.y*v.y + v.z*v.z + v.w*v.w;
  }
  for (int off = 32; off > 0; off >>= 1) s += __shfl_down(s, off);
  if (threadIdx.x == 0) dst[q] = 1.0f / fmaxf(sqrtf(s), 1e-12f);
}

// ---- split-K GEMM: P[s][q][w] = dot(feat[row(q)], proto[w]) over K-slice s -
__global__ __launch_bounds__(256)
void gemm_splitk(const float* __restrict__ feat, const float* __restrict__ proto,
                 const int* __restrict__ idxlist, float* __restrict__ P,
                 const int* nDev, int nConst)
{
  int n = nDev ? *nDev : nConst;
  int qBase = blockIdx.x * BQ;
  if (qBase >= n) return;
  int wBase = blockIdx.y * BW;
  int splitk = gridDim.z;
  int kLen = DIM / splitk;
  int kStart = blockIdx.z * kLen;

  __shared__ float As[BK][BQ+PADQ];
  __shared__ float Bs[BK][BW+PADW];

  int tid = threadIdx.x;

  // A staging: row qr = tid&127, k-chunks kk4 = (tid>>7) + 2*i  (i=0..3)
  int qr = tid & 127;
  int arow = qBase + qr;
  int garow = idxlist ? idxlist[min(arow, n-1)] : min(arow, n-1);
  const float* pA = feat + (size_t)garow*DIM + kStart;
  int akk0 = tid >> 7;              // 0..1

  // B staging: row wr = tid&63, k-chunks kk4 = (tid>>6) + 4*i  (i=0..1)
  int wr = tid & 63;
  int gbrow = wBase + wr;
  bool bok = (gbrow < WAYS);
  const float* pB = proto + (size_t)gbrow*DIM + kStart;
  int bkk0 = tid >> 6;              // 0..3

  int tx = tid & 15;                // w: tx*4
  int ty = tid >> 4;                // q: ty*8
  float acc[8][4];
#pragma unroll
  for (int i = 0; i < 8; i++)
#pragma unroll
    for (int j = 0; j < 4; j++) acc[i][j] = 0.f;

  for (int k0 = 0; k0 < kLen; k0 += BK){
    float4 av[4], bv[2];
#pragma unroll
    for (int i = 0; i < 4; i++)
      av[i] = *(const float4*)(pA + k0 + (akk0 + 2*i)*4);
#pragma unroll
    for (int i = 0; i < 2; i++)
      bv[i] = bok ? *(const float4*)(pB + k0 + (bkk0 + 4*i)*4)
                  : make_float4(0.f,0.f,0.f,0.f);
    __syncthreads();
#pragma unroll
    for (int i = 0; i < 4; i++){
      int kk = (akk0 + 2*i)*4;
      As[kk+0][qr] = av[i].x; As[kk+1][qr] = av[i].y;
      As[kk+2][qr] = av[i].z; As[kk+3][qr] = av[i].w;
    }
#pragma unroll
    for (int i = 0; i < 2; i++){
      int kk = (bkk0 + 4*i)*4;
      Bs[kk+0][wr] = bv[i].x; Bs[kk+1][wr] = bv[i].y;
      Bs[kk+2][wr] = bv[i].z; Bs[kk+3][wr] = bv[i].w;
    }
    __syncthreads();
#pragma unroll
    for (int kk2 = 0; kk2 < BK; kk2++){
      float4 a0 = *(const float4*)&As[kk2][ty*8];
      float4 a1 = *(const float4*)&As[kk2][ty*8+4];
      float4 b0 = *(const float4*)&Bs[kk2][tx*4];
      float a8[8] = {a0.x,a0.y,a0.z,a0.w,a1.x,a1.y,a1.z,a1.w};
      float b4[4] = {b0.x,b0.y,b0.z,b0.w};
#pragma unroll
      for (int i = 0; i < 8; i++)
#pragma unroll
        for (int j = 0; j < 4; j++)
          acc[i][j] += a8[i]*b4[j];
    }
  }
  float* Pb = P + (size_t)blockIdx.z * NQ * WAYS;
  int wc = wBase + tx*4;
#pragma unroll
  for (int i = 0; i < 8; i++){
    int q = qBase + ty*8 + i;
    if (q >= n) continue;
    float* dst = Pb + (size_t)q*WAYS + wc;
    if (wc + 3 < WAYS){
      *(float4*)dst = make_float4(acc[i][0], acc[i][1], acc[i][2], acc[i][3]);
    } else {
#pragma unroll
      for (int j = 0; j < 4; j++) if (wc + j < WAYS) dst[j] = acc[i][j];
    }
  }
}

// ---- combine K-slices (fixed order -> deterministic), apply invn, colSq ----
__global__ __launch_bounds__(256)
void combine_kernel(const float* __restrict__ P, int splitk,
                    const float* __restrict__ invn, const int* __restrict__ idxlist,
                    const int* nDev, int nConst, float* L, double* colSq)
{
  int n = nDev ? *nDev : nConst;
  int q = blockIdx.x*256 + threadIdx.x;
  __shared__ float lsq[WAYS];
  if (threadIdx.x < WAYS) lsq[threadIdx.x] = 0.f;
  __syncthreads();
  if (q < n){
    int gq = idxlist ? idxlist[q] : q;
    float sc = invn[gq];
    const float* p0 = P + (size_t)q*WAYS;
    float* lrow = L + (size_t)q*WAYS;
    for (int w = 0; w < WAYS; w += 4){
      float4 v = *(const float4*)(p0 + w);
      for (int t = 1; t < splitk; t++){
        float4 u = *(const float4*)(p0 + (size_t)t*NQ*WAYS + w);
        v.x += u.x; v.y += u.y; v.z += u.z; v.w += u.w;
      }
      v.x *= sc; v.y *= sc; v.z *= sc; v.w *= sc;
      *(float4*)(lrow + w) = v;
      atomicAdd(&lsq[w+0], v.x*v.x);
      atomicAdd(&lsq[w+1], v.y*v.y);
      atomicAdd(&lsq[w+2], v.z*v.z);
      atomicAdd(&lsq[w+3], v.w*v.w);
    }
  }
  __syncthreads();
  if (threadIdx.x < WAYS) atomicAdd(&colSq[threadIdx.x], (double)lsq[threadIdx.x]);
}

// ---- per-row max/argmax with lazy scale ------------------------------------
__global__ void rowstats1_kernel(const float* __restrict__ L, const double* colSq,
                                 const float* tpP, const int* nDev, int nConst,
                                 float* __restrict__ absCert,
                                 unsigned int* __restrict__ keys, int* __restrict__ pseudo){
  __shared__ float sc[WAYS];
  int n = nDev ? *nDev : nConst;
  if (threadIdx.x < WAYS)
    sc[threadIdx.x] = (*tpP) / ((float)sqrt(colSq[threadIdx.x]) + 1e-6f);
  __syncthreads();
  int q = blockIdx.x*256 + threadIdx.x;
  if (q >= n) return;
  const float* row = L + (size_t)q*WAYS;
  float m = row[0]*sc[0]; int am = 0;
  for (int w = 1; w < WAYS; w++){
    float v = row[w]*sc[w];
    if (v > m){ m = v; am = w; }
  }
  absCert[q] = m; pseudo[q] = am; keys[q] = monokey(m);
}

// ---- per-row max + negative entropy (full runs), lazy scale ----------------
__global__ void rowstats2_kernel(const float* __restrict__ L, const double* colSq,
                                 const float* tpP,
                                 float* __restrict__ absC, float* __restrict__ relC){
  __shared__ float sc[WAYS];
  if (threadIdx.x < WAYS)
    sc[threadIdx.x] = (*tpP) / ((float)sqrt(colSq[threadIdx.x]) + 1e-6f);
  __syncthreads();
  int q = blockIdx.x*256 + threadIdx.x;
  if (q >= NQ) return;
  const float* row = L + (size_t)q*WAYS;
  float m = row[0]*sc[0];
  for (int w = 1; w < WAYS; w++) m = fmaxf(m, row[w]*sc[w]);
  float s = 0.f;
  for (int w = 0; w < WAYS; w++) s += expf(row[w]*sc[w] - m);
  float inv = 1.0f / s, rel = 0.f;
  for (int w = 0; w < WAYS; w++){
    float p = expf(row[w]*sc[w] - m) * inv;
    rel += p * logf(p + 1e-10f);
  }
  absC[q] = m; relC[q] = rel;
}

// ---- fused radix-select + deterministic stable gather ----------------------
__global__ __launch_bounds__(1024)
void selectgather_kernel(const unsigned int* __restrict__ keys,
                         const float* __restrict__ absCert,
                         const int* nDev, int nConst, Ctrl* ctrl, int inst,
                         int* __restrict__ selIdx, float* __restrict__ selVal)
{
  int n = nDev ? *nDev : nConst;
  int k = n < KSEL ? n : KSEL;
  __shared__ int hist[256];
  __shared__ unsigned int sprefix;
  __shared__ int srem;
  int t = threadIdx.x;
  if (t == 0){ sprefix = 0u; srem = k; }
  __syncthreads();
  for (int pass = 0; pass < 4; pass++){
    int shift = 24 - 8*pass;
    if (t < 256) hist[t] = 0;
    __syncthreads();
    unsigned int pref = sprefix;
    unsigned int mask = (pass == 0) ? 0u : (0xFFFFFFFFu << (shift + 8));
    for (int i = t; i < n; i += 1024){
      unsigned int key = keys[i];
      if ((key & mask) == pref) atomicAdd(&hist[(key >> shift) & 255], 1);
    }
    __syncthreads();
    if (t == 0){
      int acc = 0, rem = srem, sel = 0;
      for (int b2 = 255; b2 >= 0; b2--){
        int h = hist[b2];
        if (acc + h >= rem){ sel = b2; srem = rem - acc; break; }
        acc += h;
      }
      sprefix = pref | ((unsigned int)sel << shift);
    }
    __syncthreads();
  }
  unsigned int T = sprefix;
  int rem = srem;
  if (t == 0){ ctrl->T[inst] = T; ctrl->rem[inst] = rem; ctrl->kk[inst] = k; }
  int cntGT = k - rem;
  const int CH = 10;
  int q0 = t*CH;
  int fg[CH], fe[CH]; int cg = 0, ce = 0;
  for (int i = 0; i < CH; i++){
    int q = q0 + i; int g = 0, e = 0;
    if (q < n){ unsigned int key = keys[q]; g = key > T; e = (key == T); }
    fg[i] = g; fe[i] = e; cg += g; ce += e;
  }
  __shared__ int sG[1024], sE[1024];
  sG[t] = cg; sE[t] = ce; __syncthreads();
  for (int s = 1; s < 1024; s <<= 1){
    int vg = t >= s ? sG[t-s] : 0;
    int ve = t >= s ? sE[t-s] : 0;
    __syncthreads();
    sG[t] += vg; sE[t] += ve;
    __syncthreads();
  }
  int posG = sG[t] - cg, posE = sE[t] - ce;
  for (int i = 0; i < CH; i++){
    int q = q0 + i;
    if (q >= n) break;
    if (fg[i]){ selIdx[posG] = q; selVal[posG] = absCert[q]; posG++; }
    else if (fe[i]){
      if (posE < rem){ selIdx[cntGT+posE] = q; selVal[cntGT+posE] = absCert[q]; }
      posE++;
    }
  }
}

// ---- deterministic proto refine --------------------------------------------
__global__ void refine_kernel(const float* __restrict__ feat, const int* __restrict__ idxlist,
                              const float* __restrict__ invn, const float* __restrict__ proto,
                              const int* __restrict__ selIdx, const float* __restrict__ selVal,
                              const int* __restrict__ pseudo, const Ctrl* ctrl,
                              int inst, float* __restrict__ protoRef){
  int w = blockIdx.x;
  int k = ctrl->kk[inst];
  float acc[DIM/256];
#pragma unroll
  for (int i = 0; i < DIM/256; i++) acc[i] = 0.f;
  for (int j = 0; j < k; j++){
    int srow = selIdx[j];
    if (pseudo[srow] != w) continue;
    int grow = idxlist ? idxlist[srow] : srow;
    float coef = selVal[j] * invn[grow] / (float)k;
    const float* fr = feat + (size_t)grow*DIM;
#pragma unroll
    for (int i = 0; i < DIM/256; i++)
      acc[i] += coef * fr[threadIdx.x + i*256];
  }
  const float* pw = proto + (size_t)w*DIM;
  float* pr = protoRef + (size_t)w*DIM;
#pragma unroll
  for (int i = 0; i < DIM/256; i++)
    pr[threadIdx.x + i*256] = pw[threadIdx.x + i*256] + acc[i];
}

// ---- diff sign partition + index + w_r/w_f outputs -------------------------
__global__ __launch_bounds__(1024)
void diff_partition(const float* __restrict__ absCx, const float* __restrict__ relCx,
                    const float* __restrict__ absCd, const float* __restrict__ relCd,
                    Ctrl* ctrl, int* __restrict__ resIdx, int* __restrict__ dctIdx,
                    float* __restrict__ out){
  const int CH = 10;
  int t = threadIdx.x, q0 = t*CH;
  int fr[CH], fd[CH]; int cr = 0, cd = 0;
  for (int i = 0; i < CH; i++){
    int q = q0 + i; int r = 0, dn = 0;
    if (q < NQ){
      float dv = absCx[q] - absCd[q] + relCx[q] - relCd[q];
      r = dv > 0.f; dn = dv < 0.f;
    }
    fr[i] = r; fd[i] = dn; cr += r; cd += dn;
  }
  __shared__ int sR[1024], sD[1024];
  sR[t] = cr; sD[t] = cd; __syncthreads();
  for (int s = 1; s < 1024; s <<= 1){
    int vr = t >= s ? sR[t-s] : 0;
    int vd = t >= s ? sD[t-s] : 0;
    __syncthreads();
    sR[t] += vr; sD[t] += vd;
    __syncthreads();
  }
  int R = sR[1023], Dn = sD[1023];
  int posR = sR[t] - cr, posD = sD[t] - cd;
  if (t == 0){ ctrl->R = R; ctrl->Dn = Dn; }
  for (int i = 0; i < CH; i++){
    int q = q0 + i;
    if (q >= NQ) break;
    if (fr[i]){ resIdx[posR] = q; out[2+posR] = (float)q; posR++; }
    if (fd[i]){ dctIdx[posD] = q; out[2+R+posD] = (float)q; posD++; }
  }
  for (int q = t; q < NQ; q += 1024){
    float a = absCx[q], b = absCd[q];
    float den = fmaxf(a + b, 1e-8f);
    out[2+R+Dn+q]      = a / den;
    out[2+R+Dn+NQ+q]   = b / den;
  }
}

// ---- per-way logsumexp over the query dim (lazy scale) ---------------------
__global__ void lse_kernel(const float* __restrict__ Lmat, const float* __restrict__ Hmat,
                           const double* csL, const double* csH, const float* tpP,
                           const int* nDev, float* lseL, float* lseH){
  int b = blockIdx.x;                    // 0..199
  const float* M = (b < WAYS) ? Lmat : Hmat;
  const double* cs = (b < WAYS) ? csL : csH;
  int w = (b < WAYS) ? b : b - WAYS;
  float scw = (*tpP) / ((float)sqrt(cs[w]) + 1e-6f);
  int n = *nDev;
  float m = -1e30f; double s = 0.0;
  for (int q = threadIdx.x; q < n; q += 256){
    float v = M[(size_t)q*WAYS + w] * scw;
    if (v > m){ s = s*exp((double)(m - v)) + 1.0; m = v; }
    else s += exp((double)(v - m));
  }
  __shared__ float sm[256];
  __shared__ double ss[256];
  sm[threadIdx.x] = m; ss[threadIdx.x] = s; __syncthreads();
  for (int st = 128; st > 0; st >>= 1){
    if (threadIdx.x < st){
      float m1 = sm[threadIdx.x], m2 = sm[threadIdx.x+st];
      double s1 = ss[threadIdx.x], s2 = ss[threadIdx.x+st];
      float M2 = fmaxf(m1, m2);
      ss[threadIdx.x] = s1*exp((double)(m1-M2)) + s2*exp((double)(m2-M2));
      sm[threadIdx.x] = M2;
    }
    __syncthreads();
  }
  if (threadIdx.x == 0) ((b < WAYS) ? lseL : lseH)[w] = sm[0] + (float)log(ss[0]);
}

// ---- KL sum (lazy scale) ---------------------------------------------------
__global__ void klsum_kernel(const float* __restrict__ L, const float* __restrict__ H,
                             const double* csL, const double* csH, const float* tpP,
                             const float* __restrict__ lseLp, const float* __restrict__ lseHp,
                             const int* nDev, double* accum){
  __shared__ float scL[WAYS], scH[WAYS], lL[WAYS], lH[WAYS];
  if (threadIdx.x < WAYS){
    scL[threadIdx.x] = (*tpP) / ((float)sqrt(csL[threadIdx.x]) + 1e-6f);
    scH[threadIdx.x] = (*tpP) / ((float)sqrt(csH[threadIdx.x]) + 1e-6f);
    lL[threadIdx.x] = lseLp[threadIdx.x];
    lH[threadIdx.x] = lseHp[threadIdx.x];
  }
  __syncthreads();
  int n = *nDev;
  size_t total = (size_t)n * WAYS;
  double loc = 0.0;
  for (size_t i = (size_t)blockIdx.x*256 + threadIdx.x; i < total;
       i += (size_t)gridDim.x*256){
    int w = (int)(i % WAYS);
    float lh = H[i]*scH[w] - lH[w];
    float ll = L[i]*scL[w] - lL[w];
    loc += (double)(expf(lh) * (lh - ll));
  }
  __shared__ double sd[256];
  sd[threadIdx.x] = loc; __syncthreads();
  for (int st = 128; st > 0; st >>= 1){
    if (threadIdx.x < st) sd[threadIdx.x] += sd[threadIdx.x + st];
    __syncthreads();
  }
  if (threadIdx.x == 0) atomicAdd(accum, sd[0]);
}

__global__ void wsum_kernel(const float* __restrict__ absSrc, const int* __restrict__ idxlist,
                            const int* nDev, double* acc, float* w0){
  int n = *nDev;
  double loc = 0.0;
  for (int i = blockIdx.x*256 + threadIdx.x; i < n; i += gridDim.x*256)
    loc += (double)absSrc[idxlist[i]];
  __shared__ double sd[256];
  sd[threadIdx.x] = loc; __syncthreads();
  for (int st = 128; st > 0; st >>= 1){
    if (threadIdx.x < st) sd[threadIdx.x] += sd[threadIdx.x + st];
    __syncthreads();
  }
  if (threadIdx.x == 0) atomicAdd(acc, sd[0]);
  if (blockIdx.x == 0 && threadIdx.x == 0) *w0 = absSrc[idxlist[0]];
}

__global__ void final_kernel(const Ctrl* ctrl, const float* tP, const float* tdP,
                             float* out){
  if (threadIdx.x == 0 && blockIdx.x == 0){
    float lossd = ctrl->w0[0] * (float)ctrl->klsum[0] / ((float)ctrl->wsum[0] + 1e-8f);
    float lossr = ctrl->w0[1] * (float)ctrl->klsum[1] / ((float)ctrl->wsum[1] + 1e-8f);
    out[0] = (*tP)  * lossr;   // temp * loss_resl
    out[1] = (*tdP) * lossd;   // temp_dct * loss_dctl
  }
}

extern "C" void kernel_launch(void* const* d_in, const int* in_sizes, int n_in,
                              void* d_out, int out_size, void* d_ws, size_t ws_size,
                              hipStream_t stream)
{
  const float* xs  = (const float*)d_in[0];
  const float* xq  = (const float*)d_in[1];
  const float* dsh = (const float*)d_in[2];
  const float* dq  = (const float*)d_in[3];
  const float* tpP = (const float*)d_in[4];
  const float* tP  = (const float*)d_in[5];
  const float* tdP = (const float*)d_in[6];
  float* out = (float*)d_out;

  char* base = (char*)d_ws;
  Ctrl* ctrl = (Ctrl*)base;
  double* colSqAll = (double*)(base + 512);          // 12 slots x WAYS doubles
  size_t zone = 512 + (size_t)12*WAYS*8;             // zeroed every launch
  size_t off = (zone + 255) & ~(size_t)255;
  auto alloc = [&](size_t nElem)->void*{ void* p = base + off; off += nElem*4; return p; };
  float* protoX   = (float*)alloc((size_t)WAYS*DIM);
  float* protoD   = (float*)alloc((size_t)WAYS*DIM);
  float* protoRef = (float*)alloc((size_t)WAYS*DIM);
  float* invnX    = (float*)alloc(NQ);
  float* invnD    = (float*)alloc(NQ);
  float* absCx    = (float*)alloc(NQ);
  float* relCx    = (float*)alloc(NQ);
  float* absCd    = (float*)alloc(NQ);
  float* relCd    = (float*)alloc(NQ);
  float* absCert  = (float*)alloc(NQ);
  unsigned int* keys = (unsigned int*)alloc(NQ);
  int*   pseudo   = (int*)alloc(NQ);
  float* lseL     = (float*)alloc(WAYS);
  float* lseH     = (float*)alloc(WAYS);
  float* selVal   = (float*)alloc(KSEL);
  int*   selIdx   = (int*)alloc(KSEL);
  int*   resIdx   = (int*)alloc(NQ);
  int*   dctIdx   = (int*)alloc(NQ);
  float* logitsS  = (float*)alloc((size_t)NQ*WAYS);
  float* bufA     = (float*)alloc((size_t)NQ*WAYS);
  float* bufB     = (float*)alloc((size_t)NQ*WAYS);
  if (off > ws_size) return;

  // choose split-K by available workspace (ws_size is constant across calls
  // -> identical kernel sequence every launch; graph-safe)
  float* P = (float*)(base + off);
  int splitk;
  if      (off + (size_t)8*NQ*WAYS*4 <= ws_size) splitk = 8;
  else if (off + (size_t)4*NQ*WAYS*4 <= ws_size) splitk = 4;
  else if (off + (size_t)2*NQ*WAYS*4 <= ws_size) splitk = 2;
  else { splitk = 1; P = nullptr; }                  // in-place via L buffer

  hipMemsetAsync(base, 0, zone, stream);             // ctrl + all colSq slots
  proto_kernel<<<2*WAYS, 256, 0, stream>>>(xs, dsh, protoX, protoD);
  invnorm_kernel<<<2*NQ, 64, 0, stream>>>(xq, dq, invnX, invnD);

  dim3 ggrid((NQ + BQ - 1)/BQ, (WAYS + BW - 1)/BW, splitk);

  auto run_distance = [&](const float* feat, const float* invn, const float* proto,
                          const int* idxlist, const int* nDev, int nConst,
                          float* Lbuf, int inst) -> double* {
    double* cs1 = colSqAll + (size_t)(inst*2 + 0)*WAYS;
    double* cs2 = colSqAll + (size_t)(inst*2 + 1)*WAYS;
    float* Pb = (splitk > 1) ? P : Lbuf;
    gemm_splitk<<<ggrid,256,0,stream>>>(feat, proto, idxlist, Pb, nDev, nConst);
    combine_kernel<<<(NQ+255)/256,256,0,stream>>>(Pb, splitk, invn, idxlist, nDev, nConst,
                                                  Lbuf, cs1);
    rowstats1_kernel<<<(NQ+255)/256,256,0,stream>>>(Lbuf, cs1, tpP, nDev, nConst,
                                                    absCert, keys, pseudo);
    selectgather_kernel<<<1,1024,0,stream>>>(keys, absCert, nDev, nConst, ctrl, inst,
                                             selIdx, selVal);
    refine_kernel<<<WAYS,256,0,stream>>>(feat, idxlist, invn, proto, selIdx, selVal,
                                         pseudo, ctrl, inst, protoRef);
    gemm_splitk<<<ggrid,256,0,stream>>>(feat, protoRef, idxlist, Pb, nDev, nConst);
    combine_kernel<<<(NQ+255)/256,256,0,stream>>>(Pb, splitk, invn, idxlist, nDev, nConst,
                                                  Lbuf, cs2);
    return cs2;
  };

  // full runs -> abs/rel certainties
  double* cs;
  cs = run_distance(xq, invnX, protoX, nullptr, nullptr, NQ, logitsS, 0);
  rowstats2_kernel<<<(NQ+255)/256,256,0,stream>>>(logitsS, cs, tpP, absCx, relCx);
  cs = run_distance(dq, invnD, protoD, nullptr, nullptr, NQ, logitsS, 1);
  rowstats2_kernel<<<(NQ+255)/256,256,0,stream>>>(logitsS, cs, tpP, absCd, relCd);

  diff_partition<<<1,1024,0,stream>>>(absCx, relCx, absCd, relCd, ctrl, resIdx, dctIdx, out);

  // loss_dctl = distill(ldl, lrh, absCx[res])
  double* csA = run_distance(xq, invnX, protoX, resIdx, &ctrl->R, 0, bufA, 2);   // lrh
  double* csB = run_distance(dq, invnD, protoD, resIdx, &ctrl->R, 0, bufB, 3);   // ldl
  lse_kernel<<<2*WAYS,256,0,stream>>>(bufB, bufA, csB, csA, tpP, &ctrl->R, lseL, lseH);
  klsum_kernel<<<256,256,0,stream>>>(bufB, bufA, csB, csA, tpP, lseL, lseH,
                                     &ctrl->R, &ctrl->klsum[0]);
  wsum_kernel<<<(NQ+255)/256,256,0,stream>>>(absCx, resIdx, &ctrl->R, &ctrl->wsum[0],
                                             &ctrl->w0[0]);

  // loss_resl = distill(lrl, ldh, absCd[dct])
  csA = run_distance(dq, invnD, protoD, dctIdx, &ctrl->Dn, 0, bufA, 4);          // ldh
  csB = run_distance(xq, invnX, protoX, dctIdx, &ctrl->Dn, 0, bufB, 5);          // lrl
  lse_kernel<<<2*WAYS,256,0,stream>>>(bufB, bufA, csB, csA, tpP, &ctrl->Dn, lseL, lseH);
  klsum_kernel<<<256,256,0,stream>>>(bufB, bufA, csB, csA, tpP, lseL, lseH,
                                     &ctrl->Dn, &ctrl->klsum[1]);
  wsum_kernel<<<(NQ+255)/256,256,0,stream>>>(absCd, dctIdx, &ctrl->Dn, &ctrl->wsum[1],
                                             &ctrl->w0[1]);

  final_kernel<<<1,64,0,stream>>>(ctrl, tP, tdP, out);
}

// Round 3
// 1633.635 us; speedup vs baseline: 2.8834x; 2.8834x over previous
//
#include <hip/hip_runtime.h>
#include <cstdint>
#include <cstddef>

#define WAYS  100
#define SHOTS 5
#define NQ    10000
#define DIM   2048
#define KSEL  512

#define BQ 128
#define BW 64
#define BK 32
#define PADQ 4
#define PADW 4
#define CQ 64

struct Ctrl {
  double klsum[2];   // [0]=dctl, [1]=resl
  double wsum[2];
  float  w0[2];
  int    R, Dn;
  unsigned int T[8];
  int rem[8];
  int kk[8];
};

__device__ __forceinline__ unsigned int monokey(float f){
  unsigned int b = __float_as_uint(f);
  return (b & 0x80000000u) ? ~b : (b | 0x80000000u);
}

// ---- prototypes: mean over shots, then row l2-norm -------------------------
__global__ void proto_kernel(const float* __restrict__ xs, const float* __restrict__ dsh,
                             float* __restrict__ protoX, float* __restrict__ protoD){
  int b = blockIdx.x;
  const float* src = (b < WAYS) ? xs : dsh;
  float* dst = (b < WAYS) ? protoX : protoD;
  int w = (b < WAYS) ? b : b - WAYS;
  __shared__ float meanv[DIM];
  __shared__ float red[256];
  float loc = 0.f;
  for (int d = threadIdx.x; d < DIM; d += 256){
    float s = 0.f;
    for (int sh = 0; sh < SHOTS; sh++) s += src[((size_t)w*SHOTS + sh)*DIM + d];
    float m = s / (float)SHOTS;
    meanv[d] = m;
    loc += m*m;
  }
  red[threadIdx.x] = loc; __syncthreads();
  for (int st = 128; st > 0; st >>= 1){
    if (threadIdx.x < st) red[threadIdx.x] += red[threadIdx.x + st];
    __syncthreads();
  }
  float inv = 1.0f / fmaxf(sqrtf(red[0]), 1e-12f);
  for (int d = threadIdx.x; d < DIM; d += 256)
    dst[(size_t)w*DIM + d] = meanv[d] * inv;
}

// ---- per-query inverse L2 norm ---------------------------------------------
__global__ void invnorm_kernel(const float* __restrict__ xq, const float* __restrict__ dq,
                               float* __restrict__ invnX, float* __restrict__ invnD){
  int r = blockIdx.x;                       // 0..2*NQ-1
  const float* src = (r < NQ) ? xq : dq;
  float* dst = (r < NQ) ? invnX : invnD;
  int q = (r < NQ) ? r : r - NQ;
  const float4* row = (const float4*)(src + (size_t)q*DIM);
  float s = 0.f;
  for (int i = threadIdx.x; i < DIM/4; i += 64){
    float4 v = row[i];
    s += v.x*v.x + v.y*v.y + v.z*v.z + v.w*v.w;
  }
  for (int off = 32; off > 0; off >>= 1) s += __shfl_down(s, off);
  if (threadIdx.x == 0) dst[q] = 1.0f / fmaxf(sqrtf(s), 1e-12f);
}

// ---- split-K GEMM: P[s][q][w] = dot(feat[row(q)], proto[w]) over K-slice s -
__global__ __launch_bounds__(256)
void gemm_splitk(const float* __restrict__ feat, const float* __restrict__ proto,
                 const int* __restrict__ idxlist, float* __restrict__ P,
                 const int* nDev, int nConst)
{
  int n = nDev ? *nDev : nConst;
  int qBase = blockIdx.x * BQ;
  if (qBase >= n) return;
  int wBase = blockIdx.y * BW;
  int splitk = gridDim.z;
  int kLen = DIM / splitk;
  int kStart = blockIdx.z * kLen;

  __shared__ float As[BK][BQ+PADQ];
  __shared__ float Bs[BK][BW+PADW];

  int tid = threadIdx.x;

  int qr = tid & 127;
  int arow = qBase + qr;
  int garow = idxlist ? idxlist[min(arow, n-1)] : min(arow, n-1);
  const float* pA = feat + (size_t)garow*DIM + kStart;
  int akk0 = tid >> 7;              // 0..1

  int wr = tid & 63;
  int gbrow = wBase + wr;
  bool bok = (gbrow < WAYS);
  const float* pB = proto + (size_t)gbrow*DIM + kStart;
  int bkk0 = tid >> 6;              // 0..3

  int tx = tid & 15;                // w: tx*4
  int ty = tid >> 4;                // q: ty*8
  float acc[8][4];
#pragma unroll
  for (int i = 0; i < 8; i++)
#pragma unroll
    for (int j = 0; j < 4; j++) acc[i][j] = 0.f;

  for (int k0 = 0; k0 < kLen; k0 += BK){
    float4 av[4], bv[2];
#pragma unroll
    for (int i = 0; i < 4; i++)
      av[i] = *(const float4*)(pA + k0 + (akk0 + 2*i)*4);
#pragma unroll
    for (int i = 0; i < 2; i++)
      bv[i] = bok ? *(const float4*)(pB + k0 + (bkk0 + 4*i)*4)
                  : make_float4(0.f,0.f,0.f,0.f);
    __syncthreads();
#pragma unroll
    for (int i = 0; i < 4; i++){
      int kk = (akk0 + 2*i)*4;
      As[kk+0][qr] = av[i].x; As[kk+1][qr] = av[i].y;
      As[kk+2][qr] = av[i].z; As[kk+3][qr] = av[i].w;
    }
#pragma unroll
    for (int i = 0; i < 2; i++){
      int kk = (bkk0 + 4*i)*4;
      Bs[kk+0][wr] = bv[i].x; Bs[kk+1][wr] = bv[i].y;
      Bs[kk+2][wr] = bv[i].z; Bs[kk+3][wr] = bv[i].w;
    }
    __syncthreads();
#pragma unroll
    for (int kk2 = 0; kk2 < BK; kk2++){
      float4 a0 = *(const float4*)&As[kk2][ty*8];
      float4 a1 = *(const float4*)&As[kk2][ty*8+4];
      float4 b0 = *(const float4*)&Bs[kk2][tx*4];
      float a8[8] = {a0.x,a0.y,a0.z,a0.w,a1.x,a1.y,a1.z,a1.w};
      float b4[4] = {b0.x,b0.y,b0.z,b0.w};
#pragma unroll
      for (int i = 0; i < 8; i++)
#pragma unroll
        for (int j = 0; j < 4; j++)
          acc[i][j] += a8[i]*b4[j];
    }
  }
  float* Pb = P + (size_t)blockIdx.z * NQ * WAYS;
  int wc = wBase + tx*4;
#pragma unroll
  for (int i = 0; i < 8; i++){
    int q = qBase + ty*8 + i;
    if (q >= n) continue;
    float* dst = Pb + (size_t)q*WAYS + wc;
    if (wc + 3 < WAYS){
      *(float4*)dst = make_float4(acc[i][0], acc[i][1], acc[i][2], acc[i][3]);
    } else {
#pragma unroll
      for (int j = 0; j < 4; j++) if (wc + j < WAYS) dst[j] = acc[i][j];
    }
  }
}

// ---- combine K-slices (fixed order), apply invn, colSq (no LDS atomics) ----
// layout: j = tid%25 -> w=4j (float4), r = tid/25 strides q; coalesced rows.
__global__ __launch_bounds__(256)
void combine_kernel(const float* __restrict__ P, int splitk,
                    const float* __restrict__ invn, const int* __restrict__ idxlist,
                    const int* nDev, int nConst, float* __restrict__ L,
                    double* __restrict__ colSq)
{
  int n = nDev ? *nDev : nConst;
  int qBase = blockIdx.x * CQ;
  if (qBase >= n) return;
  int t = threadIdx.x;
  int j = t % 25;            // w-group: w = 4j
  int r = t / 25;            // 0..10 (r==10 -> idle)
  double sq0 = 0.0, sq1 = 0.0, sq2 = 0.0, sq3 = 0.0;
  if (r < 10){
    for (int i = r; i < CQ; i += 10){
      int q = qBase + i;
      if (q >= n) break;
      int gq = idxlist ? idxlist[q] : q;
      float sc = invn[gq];
      const float* p0 = P + (size_t)q*WAYS + 4*j;
      float4 v = *(const float4*)p0;
      for (int s = 1; s < splitk; s++){
        float4 u = *(const float4*)(p0 + (size_t)s*NQ*WAYS);
        v.x += u.x; v.y += u.y; v.z += u.z; v.w += u.w;
      }
      v.x *= sc; v.y *= sc; v.z *= sc; v.w *= sc;
      *(float4*)(L + (size_t)q*WAYS + 4*j) = v;
      sq0 += (double)v.x*(double)v.x;
      sq1 += (double)v.y*(double)v.y;
      sq2 += (double)v.z*(double)v.z;
      sq3 += (double)v.w*(double)v.w;
    }
  }
  __shared__ double red[WAYS][10];
  if (r < 10){
    red[4*j+0][r] = sq0; red[4*j+1][r] = sq1;
    red[4*j+2][r] = sq2; red[4*j+3][r] = sq3;
  }
  __syncthreads();
  if (t < WAYS){
    double s = 0.0;
#pragma unroll
    for (int rr = 0; rr < 10; rr++) s += red[t][rr];
    atomicAdd(&colSq[t], s);
  }
}

// ---- per-row max/argmax with lazy scale ------------------------------------
__global__ void rowstats1_kernel(const float* __restrict__ L, const double* colSq,
                                 const float* tpP, const int* nDev, int nConst,
                                 float* __restrict__ absCert,
                                 unsigned int* __restrict__ keys, int* __restrict__ pseudo){
  __shared__ float sc[WAYS];
  int n = nDev ? *nDev : nConst;
  if (threadIdx.x < WAYS)
    sc[threadIdx.x] = (*tpP) / ((float)sqrt(colSq[threadIdx.x]) + 1e-6f);
  __syncthreads();
  int q = blockIdx.x*256 + threadIdx.x;
  if (q >= n) return;
  const float* row = L + (size_t)q*WAYS;
  float m = row[0]*sc[0]; int am = 0;
  for (int w = 1; w < WAYS; w++){
    float v = row[w]*sc[w];
    if (v > m){ m = v; am = w; }
  }
  absCert[q] = m; pseudo[q] = am; keys[q] = monokey(m);
}

// ---- per-row max + negative entropy (full runs), lazy scale ----------------
__global__ void rowstats2_kernel(const float* __restrict__ L, const double* colSq,
                                 const float* tpP,
                                 float* __restrict__ absC, float* __restrict__ relC){
  __shared__ float sc[WAYS];
  if (threadIdx.x < WAYS)
    sc[threadIdx.x] = (*tpP) / ((float)sqrt(colSq[threadIdx.x]) + 1e-6f);
  __syncthreads();
  int q = blockIdx.x*256 + threadIdx.x;
  if (q >= NQ) return;
  const float* row = L + (size_t)q*WAYS;
  float m = row[0]*sc[0];
  for (int w = 1; w < WAYS; w++) m = fmaxf(m, row[w]*sc[w]);
  float s = 0.f;
  for (int w = 0; w < WAYS; w++) s += expf(row[w]*sc[w] - m);
  float inv = 1.0f / s, rel = 0.f;
  for (int w = 0; w < WAYS; w++){
    float p = expf(row[w]*sc[w] - m) * inv;
    rel += p * logf(p + 1e-10f);
  }
  absC[q] = m; relC[q] = rel;
}

// ---- fused radix-select + deterministic stable gather ----------------------
__global__ __launch_bounds__(1024)
void selectgather_kernel(const unsigned int* __restrict__ keys,
                         const float* __restrict__ absCert,
                         const int* nDev, int nConst, Ctrl* ctrl, int inst,
                         int* __restrict__ selIdx, float* __restrict__ selVal)
{
  int n = nDev ? *nDev : nConst;
  int k = n < KSEL ? n : KSEL;
  __shared__ int hist[256];
  __shared__ unsigned int sprefix;
  __shared__ int srem;
  int t = threadIdx.x;
  if (t == 0){ sprefix = 0u; srem = k; }
  __syncthreads();
  int nv4 = n >> 2;
  for (int pass = 0; pass < 4; pass++){
    int shift = 24 - 8*pass;
    if (t < 256) hist[t] = 0;
    __syncthreads();
    unsigned int pref = sprefix;
    unsigned int mask = (pass == 0) ? 0u : (0xFFFFFFFFu << (shift + 8));
    for (int i = t; i < nv4; i += 1024){
      uint4 kv = ((const uint4*)keys)[i];
      if ((kv.x & mask) == pref) atomicAdd(&hist[(kv.x >> shift) & 255], 1);
      if ((kv.y & mask) == pref) atomicAdd(&hist[(kv.y >> shift) & 255], 1);
      if ((kv.z & mask) == pref) atomicAdd(&hist[(kv.z >> shift) & 255], 1);
      if ((kv.w & mask) == pref) atomicAdd(&hist[(kv.w >> shift) & 255], 1);
    }
    for (int i = 4*nv4 + t; i < n; i += 1024){
      unsigned int key = keys[i];
      if ((key & mask) == pref) atomicAdd(&hist[(key >> shift) & 255], 1);
    }
    __syncthreads();
    if (t == 0){
      int acc = 0, rem = srem, sel = 0;
      for (int b2 = 255; b2 >= 0; b2--){
        int h = hist[b2];
        if (acc + h >= rem){ sel = b2; srem = rem - acc; break; }
        acc += h;
      }
      sprefix = pref | ((unsigned int)sel << shift);
    }
    __syncthreads();
  }
  unsigned int T = sprefix;
  int rem = srem;
  if (t == 0){ ctrl->T[inst] = T; ctrl->rem[inst] = rem; ctrl->kk[inst] = k; }
  int cntGT = k - rem;
  const int CH = 10;
  int q0 = t*CH;
  int fg[CH], fe[CH]; int cg = 0, ce = 0;
  for (int i = 0; i < CH; i++){
    int q = q0 + i; int g = 0, e = 0;
    if (q < n){ unsigned int key = keys[q]; g = key > T; e = (key == T); }
    fg[i] = g; fe[i] = e; cg += g; ce += e;
  }
  __shared__ int sG[1024], sE[1024];
  sG[t] = cg; sE[t] = ce; __syncthreads();
  for (int s = 1; s < 1024; s <<= 1){
    int vg = t >= s ? sG[t-s] : 0;
    int ve = t >= s ? sE[t-s] : 0;
    __syncthreads();
    sG[t] += vg; sE[t] += ve;
    __syncthreads();
  }
  int posG = sG[t] - cg, posE = sE[t] - ce;
  for (int i = 0; i < CH; i++){
    int q = q0 + i;
    if (q >= n) break;
    if (fg[i]){ selIdx[posG] = q; selVal[posG] = absCert[q]; posG++; }
    else if (fe[i]){
      if (posE < rem){ selIdx[cntGT+posE] = q; selVal[cntGT+posE] = absCert[q]; }
      posE++;
    }
  }
}

// ---- deterministic proto refine (LDS-staged index scan) --------------------
__global__ __launch_bounds__(256)
void refine_kernel(const float* __restrict__ feat, const int* __restrict__ idxlist,
                   const float* __restrict__ invn, const float* __restrict__ proto,
                   const int* __restrict__ selIdx, const float* __restrict__ selVal,
                   const int* __restrict__ pseudo, const Ctrl* ctrl,
                   int inst, float* __restrict__ protoRef){
  int w = blockIdx.x;
  int k = ctrl->kk[inst];
  __shared__ int   sRow[KSEL];    // global row index of selected sample
  __shared__ float sCoef[KSEL];
  int t = threadIdx.x;
  for (int j = t; j < k; j += 256){
    int srow = selIdx[j];
    int grow = idxlist ? idxlist[srow] : srow;
    sRow[j]  = (pseudo[srow] == w) ? grow : -1;
    sCoef[j] = selVal[j] * invn[grow] / (float)k;
  }
  __syncthreads();
  float4 acc0 = make_float4(0.f,0.f,0.f,0.f);
  float4 acc1 = make_float4(0.f,0.f,0.f,0.f);
  int d0 = t*4, d1 = t*4 + 1024;
  for (int j = 0; j < k; j++){
    int grow = sRow[j];
    if (grow < 0) continue;
    float c = sCoef[j];
    const float* fr = feat + (size_t)grow*DIM;
    float4 f0 = *(const float4*)(fr + d0);
    float4 f1 = *(const float4*)(fr + d1);
    acc0.x += c*f0.x; acc0.y += c*f0.y; acc0.z += c*f0.z; acc0.w += c*f0.w;
    acc1.x += c*f1.x; acc1.y += c*f1.y; acc1.z += c*f1.z; acc1.w += c*f1.w;
  }
  const float* pw = proto + (size_t)w*DIM;
  float* pr = protoRef + (size_t)w*DIM;
  float4 p0 = *(const float4*)(pw + d0);
  float4 p1 = *(const float4*)(pw + d1);
  *(float4*)(pr + d0) = make_float4(p0.x+acc0.x, p0.y+acc0.y, p0.z+acc0.z, p0.w+acc0.w);
  *(float4*)(pr + d1) = make_float4(p1.x+acc1.x, p1.y+acc1.y, p1.z+acc1.z, p1.w+acc1.w);
}

// ---- diff sign partition + index + w_r/w_f outputs -------------------------
__global__ __launch_bounds__(1024)
void diff_partition(const float* __restrict__ absCx, const float* __restrict__ relCx,
                    const float* __restrict__ absCd, const float* __restrict__ relCd,
                    Ctrl* ctrl, int* __restrict__ resIdx, int* __restrict__ dctIdx,
                    float* __restrict__ out){
  const int CH = 10;
  int t = threadIdx.x, q0 = t*CH;
  int fr[CH], fd[CH]; int cr = 0, cd = 0;
  for (int i = 0; i < CH; i++){
    int q = q0 + i; int r = 0, dn = 0;
    if (q < NQ){
      float dv = absCx[q] - absCd[q] + relCx[q] - relCd[q];
      r = dv > 0.f; dn = dv < 0.f;
    }
    fr[i] = r; fd[i] = dn; cr += r; cd += dn;
  }
  __shared__ int sR[1024], sD[1024];
  sR[t] = cr; sD[t] = cd; __syncthreads();
  for (int s = 1; s < 1024; s <<= 1){
    int vr = t >= s ? sR[t-s] : 0;
    int vd = t >= s ? sD[t-s] : 0;
    __syncthreads();
    sR[t] += vr; sD[t] += vd;
    __syncthreads();
  }
  int R = sR[1023], Dn = sD[1023];
  int posR = sR[t] - cr, posD = sD[t] - cd;
  if (t == 0){ ctrl->R = R; ctrl->Dn = Dn; }
  for (int i = 0; i < CH; i++){
    int q = q0 + i;
    if (q >= NQ) break;
    if (fr[i]){ resIdx[posR] = q; out[2+posR] = (float)q; posR++; }
    if (fd[i]){ dctIdx[posD] = q; out[2+R+posD] = (float)q; posD++; }
  }
  for (int q = t; q < NQ; q += 1024){
    float a = absCx[q], b = absCd[q];
    float den = fmaxf(a + b, 1e-8f);
    out[2+R+Dn+q]      = a / den;
    out[2+R+Dn+NQ+q]   = b / den;
  }
}

// ---- per-way logsumexp over the query dim (lazy scale) ---------------------
__global__ void lse_kernel(const float* __restrict__ Lmat, const float* __restrict__ Hmat,
                           const double* csL, const double* csH, const float* tpP,
                           const int* nDev, float* lseL, float* lseH){
  int b = blockIdx.x;                    // 0..199
  const float* M = (b < WAYS) ? Lmat : Hmat;
  const double* cs = (b < WAYS) ? csL : csH;
  int w = (b < WAYS) ? b : b - WAYS;
  float scw = (*tpP) / ((float)sqrt(cs[w]) + 1e-6f);
  int n = *nDev;
  float m = -1e30f; double s = 0.0;
  for (int q = threadIdx.x; q < n; q += 256){
    float v = M[(size_t)q*WAYS + w] * scw;
    if (v > m){ s = s*exp((double)(m - v)) + 1.0; m = v; }
    else s += exp((double)(v - m));
  }
  __shared__ float sm[256];
  __shared__ double ss[256];
  sm[threadIdx.x] = m; ss[threadIdx.x] = s; __syncthreads();
  for (int st = 128; st > 0; st >>= 1){
    if (threadIdx.x < st){
      float m1 = sm[threadIdx.x], m2 = sm[threadIdx.x+st];
      double s1 = ss[threadIdx.x], s2 = ss[threadIdx.x+st];
      float M2 = fmaxf(m1, m2);
      ss[threadIdx.x] = s1*exp((double)(m1-M2)) + s2*exp((double)(m2-M2));
      sm[threadIdx.x] = M2;
    }
    __syncthreads();
  }
  if (threadIdx.x == 0) ((b < WAYS) ? lseL : lseH)[w] = sm[0] + (float)log(ss[0]);
}

// ---- KL sum (lazy scale) ---------------------------------------------------
__global__ void klsum_kernel(const float* __restrict__ L, const float* __restrict__ H,
                             const double* csL, const double* csH, const float* tpP,
                             const float* __restrict__ lseLp, const float* __restrict__ lseHp,
                             const int* nDev, double* accum){
  __shared__ float scL[WAYS], scH[WAYS], lL[WAYS], lH[WAYS];
  if (threadIdx.x < WAYS){
    scL[threadIdx.x] = (*tpP) / ((float)sqrt(csL[threadIdx.x]) + 1e-6f);
    scH[threadIdx.x] = (*tpP) / ((float)sqrt(csH[threadIdx.x]) + 1e-6f);
    lL[threadIdx.x] = lseLp[threadIdx.x];
    lH[threadIdx.x] = lseHp[threadIdx.x];
  }
  __syncthreads();
  int n = *nDev;
  size_t total = (size_t)n * WAYS;
  double loc = 0.0;
  for (size_t i = (size_t)blockIdx.x*256 + threadIdx.x; i < total;
       i += (size_t)gridDim.x*256){
    int w = (int)(i % WAYS);
    float lh = H[i]*scH[w] - lH[w];
    float ll = L[i]*scL[w] - lL[w];
    loc += (double)(expf(lh) * (lh - ll));
  }
  __shared__ double sd[256];
  sd[threadIdx.x] = loc; __syncthreads();
  for (int st = 128; st > 0; st >>= 1){
    if (threadIdx.x < st) sd[threadIdx.x] += sd[threadIdx.x + st];
    __syncthreads();
  }
  if (threadIdx.x == 0) atomicAdd(accum, sd[0]);
}

__global__ void wsum_kernel(const float* __restrict__ absSrc, const int* __restrict__ idxlist,
                            const int* nDev, double* acc, float* w0){
  int n = *nDev;
  double loc = 0.0;
  for (int i = blockIdx.x*256 + threadIdx.x; i < n; i += gridDim.x*256)
    loc += (double)absSrc[idxlist[i]];
  __shared__ double sd[256];
  sd[threadIdx.x] = loc; __syncthreads();
  for (int st = 128; st > 0; st >>= 1){
    if (threadIdx.x < st) sd[threadIdx.x] += sd[threadIdx.x + st];
    __syncthreads();
  }
  if (threadIdx.x == 0) atomicAdd(acc, sd[0]);
  if (blockIdx.x == 0 && threadIdx.x == 0 && n > 0) *w0 = absSrc[idxlist[0]];
}

__global__ void final_kernel(const Ctrl* ctrl, const float* tP, const float* tdP,
                             float* out){
  if (threadIdx.x == 0 && blockIdx.x == 0){
    float lossd = ctrl->w0[0] * (float)ctrl->klsum[0] / ((float)ctrl->wsum[0] + 1e-8f);
    float lossr = ctrl->w0[1] * (float)ctrl->klsum[1] / ((float)ctrl->wsum[1] + 1e-8f);
    out[0] = (*tP)  * lossr;   // temp * loss_resl
    out[1] = (*tdP) * lossd;   // temp_dct * loss_dctl
  }
}

extern "C" void kernel_launch(void* const* d_in, const int* in_sizes, int n_in,
                              void* d_out, int out_size, void* d_ws, size_t ws_size,
                              hipStream_t stream)
{
  const float* xs  = (const float*)d_in[0];
  const float* xq  = (const float*)d_in[1];
  const float* dsh = (const float*)d_in[2];
  const float* dq  = (const float*)d_in[3];
  const float* tpP = (const float*)d_in[4];
  const float* tP  = (const float*)d_in[5];
  const float* tdP = (const float*)d_in[6];
  float* out = (float*)d_out;

  char* base = (char*)d_ws;
  Ctrl* ctrl = (Ctrl*)base;
  double* colSqAll = (double*)(base + 512);          // 12 slots x WAYS doubles
  size_t zone = 512 + (size_t)12*WAYS*8;             // zeroed every launch
  size_t off = (zone + 255) & ~(size_t)255;
  auto alloc = [&](size_t nElem)->void*{ void* p = base + off; off += nElem*4; return p; };
  float* protoX   = (float*)alloc((size_t)WAYS*DIM);
  float* protoD   = (float*)alloc((size_t)WAYS*DIM);
  float* protoRef = (float*)alloc((size_t)WAYS*DIM);
  float* invnX    = (float*)alloc(NQ);
  float* invnD    = (float*)alloc(NQ);
  float* absCx    = (float*)alloc(NQ);
  float* relCx    = (float*)alloc(NQ);
  float* absCd    = (float*)alloc(NQ);
  float* relCd    = (float*)alloc(NQ);
  float* absCert  = (float*)alloc(NQ);
  unsigned int* keys = (unsigned int*)alloc(NQ);
  int*   pseudo   = (int*)alloc(NQ);
  float* lseL     = (float*)alloc(WAYS);
  float* lseH     = (float*)alloc(WAYS);
  float* selVal   = (float*)alloc(KSEL);
  int*   selIdx   = (int*)alloc(KSEL);
  int*   resIdx   = (int*)alloc(NQ);
  int*   dctIdx   = (int*)alloc(NQ);
  float* logitsS  = (float*)alloc((size_t)NQ*WAYS);
  float* bufA     = (float*)alloc((size_t)NQ*WAYS);
  float* bufB     = (float*)alloc((size_t)NQ*WAYS);
  if (off > ws_size) return;

  float* P = (float*)(base + off);
  int splitk;
  if      (off + (size_t)8*NQ*WAYS*4 <= ws_size) splitk = 8;
  else if (off + (size_t)4*NQ*WAYS*4 <= ws_size) splitk = 4;
  else if (off + (size_t)2*NQ*WAYS*4 <= ws_size) splitk = 2;
  else { splitk = 1; P = nullptr; }

  hipMemsetAsync(base, 0, zone, stream);             // ctrl + all colSq slots
  proto_kernel<<<2*WAYS, 256, 0, stream>>>(xs, dsh, protoX, protoD);
  invnorm_kernel<<<2*NQ, 64, 0, stream>>>(xq, dq, invnX, invnD);

  dim3 ggrid((NQ + BQ - 1)/BQ, (WAYS + BW - 1)/BW, splitk);
  int cgrid = (NQ + CQ - 1)/CQ;

  auto run_distance = [&](const float* feat, const float* invn, const float* proto,
                          const int* idxlist, const int* nDev, int nConst,
                          float* Lbuf, int inst) -> double* {
    double* cs1 = colSqAll + (size_t)(inst*2 + 0)*WAYS;
    double* cs2 = colSqAll + (size_t)(inst*2 + 1)*WAYS;
    float* Pb = (splitk > 1) ? P : Lbuf;
    gemm_splitk<<<ggrid,256,0,stream>>>(feat, proto, idxlist, Pb, nDev, nConst);
    combine_kernel<<<cgrid,256,0,stream>>>(Pb, splitk, invn, idxlist, nDev, nConst,
                                           Lbuf, cs1);
    rowstats1_kernel<<<(NQ+255)/256,256,0,stream>>>(Lbuf, cs1, tpP, nDev, nConst,
                                                    absCert, keys, pseudo);
    selectgather_kernel<<<1,1024,0,stream>>>(keys, absCert, nDev, nConst, ctrl, inst,
                                             selIdx, selVal);
    refine_kernel<<<WAYS,256,0,stream>>>(feat, idxlist, invn, proto, selIdx, selVal,
                                         pseudo, ctrl, inst, protoRef);
    gemm_splitk<<<ggrid,256,0,stream>>>(feat, protoRef, idxlist, Pb, nDev, nConst);
    combine_kernel<<<cgrid,256,0,stream>>>(Pb, splitk, invn, idxlist, nDev, nConst,
                                           Lbuf, cs2);
    return cs2;
  };

  // full runs -> abs/rel certainties
  double* cs;
  cs = run_distance(xq, invnX, protoX, nullptr, nullptr, NQ, logitsS, 0);
  rowstats2_kernel<<<(NQ+255)/256,256,0,stream>>>(logitsS, cs, tpP, absCx, relCx);
  cs = run_distance(dq, invnD, protoD, nullptr, nullptr, NQ, logitsS, 1);
  rowstats2_kernel<<<(NQ+255)/256,256,0,stream>>>(logitsS, cs, tpP, absCd, relCd);

  diff_partition<<<1,1024,0,stream>>>(absCx, relCx, absCd, relCd, ctrl, resIdx, dctIdx, out);

  // loss_dctl = distill(ldl, lrh, absCx[res])
  double* csA = run_distance(xq, invnX, protoX, resIdx, &ctrl->R, 0, bufA, 2);   // lrh
  double* csB = run_distance(dq, invnD, protoD, resIdx, &ctrl->R, 0, bufB, 3);   // ldl
  lse_kernel<<<2*WAYS,256,0,stream>>>(bufB, bufA, csB, csA, tpP, &ctrl->R, lseL, lseH);
  klsum_kernel<<<256,256,0,stream>>>(bufB, bufA, csB, csA, tpP, lseL, lseH,
                                     &ctrl->R, &ctrl->klsum[0]);
  wsum_kernel<<<(NQ+255)/256,256,0,stream>>>(absCx, resIdx, &ctrl->R, &ctrl->wsum[0],
                                             &ctrl->w0[0]);

  // loss_resl = distill(lrl, ldh, absCd[dct])
  csA = run_distance(dq, invnD, protoD, dctIdx, &ctrl->Dn, 0, bufA, 4);          // ldh
  csB = run_distance(xq, invnX, protoX, dctIdx, &ctrl->Dn, 0, bufB, 5);          // lrl
  lse_kernel<<<2*WAYS,256,0,stream>>>(bufB, bufA, csB, csA, tpP, &ctrl->Dn, lseL, lseH);
  klsum_kernel<<<256,256,0,stream>>>(bufB, bufA, csB, csA, tpP, lseL, lseH,
                                     &ctrl->Dn, &ctrl->klsum[1]);
  wsum_kernel<<<(NQ+255)/256,256,0,stream>>>(absCd, dctIdx, &ctrl->Dn, &ctrl->wsum[1],
                                             &ctrl->w0[1]);

  final_kernel<<<1,64,0,stream>>>(ctrl, tP, tdP, out);
}

// Round 4
// 1028.202 us; speedup vs baseline: 4.5812x; 1.5888x over previous
//
#include <hip/hip_runtime.h>
#include <cstdint>
#include <cstddef>

#define WAYS  100
#define SHOTS 5
#define NQ    10000
#define DIM   2048
#define KSEL  512

#define BQ 128
#define BW 64
#define BK 32
#define PADQ 4
#define PADW 4
#define CQ 64

struct Ctrl {
  double klsum[2];   // [0]=dctl, [1]=resl
  double wsum[2];
  float  w0[2];
  int    R, Dn;
  unsigned int T[8];
  int rem[8];
  int kk[8];
};

__device__ __forceinline__ unsigned int monokey(float f){
  unsigned int b = __float_as_uint(f);
  return (b & 0x80000000u) ? ~b : (b | 0x80000000u);
}
__device__ __forceinline__ float dekey(unsigned int k){
  return (k & 0x80000000u) ? __uint_as_float(k & 0x7FFFFFFFu)
                           : __uint_as_float(~k);
}
__device__ __forceinline__ int decn(int sel, const Ctrl* c){
  return sel == 0 ? NQ : (sel == 1 ? c->R : c->Dn);
}

// ---- prototypes: mean over shots, then row l2-norm -------------------------
__global__ void proto_kernel(const float* __restrict__ xs, const float* __restrict__ dsh,
                             float* __restrict__ protoX, float* __restrict__ protoD){
  int b = blockIdx.x;
  const float* src = (b < WAYS) ? xs : dsh;
  float* dst = (b < WAYS) ? protoX : protoD;
  int w = (b < WAYS) ? b : b - WAYS;
  __shared__ float meanv[DIM];
  __shared__ float red[256];
  float loc = 0.f;
  for (int d = threadIdx.x; d < DIM; d += 256){
    float s = 0.f;
    for (int sh = 0; sh < SHOTS; sh++) s += src[((size_t)w*SHOTS + sh)*DIM + d];
    float m = s / (float)SHOTS;
    meanv[d] = m;
    loc += m*m;
  }
  red[threadIdx.x] = loc; __syncthreads();
  for (int st = 128; st > 0; st >>= 1){
    if (threadIdx.x < st) red[threadIdx.x] += red[threadIdx.x + st];
    __syncthreads();
  }
  float inv = 1.0f / fmaxf(sqrtf(red[0]), 1e-12f);
  for (int d = threadIdx.x; d < DIM; d += 256)
    dst[(size_t)w*DIM + d] = meanv[d] * inv;
}

// ---- per-query inverse L2 norm (4 rows / 256-thread block) -----------------
__global__ __launch_bounds__(256)
void invnorm_kernel(const float* __restrict__ xq, const float* __restrict__ dq,
                    float* __restrict__ invnX, float* __restrict__ invnD){
  int row = blockIdx.x * 4 + (threadIdx.x >> 6);
  if (row >= 2*NQ) return;
  int lane = threadIdx.x & 63;
  const float* src = (row < NQ) ? xq : dq;
  float* dst = (row < NQ) ? invnX : invnD;
  int q = (row < NQ) ? row : row - NQ;
  const float4* r4 = (const float4*)(src + (size_t)q*DIM);
  float s = 0.f;
  for (int i = lane; i < DIM/4; i += 64){
    float4 v = r4[i];
    s += v.x*v.x + v.y*v.y + v.z*v.z + v.w*v.w;
  }
  for (int off = 32; off > 0; off >>= 1) s += __shfl_down(s, off);
  if (lane == 0) dst[q] = 1.0f / fmaxf(sqrtf(s), 1e-12f);
}

// ---- batched split-K GEMM with register prefetch ---------------------------
struct GemmArgs {
  const float* feat[4];
  const float* proto[4];
  const int*   idx[4];
  float*       outP[4];      // slice base per batch; slice stride NQ*WAYS
  const float* invn[4];
  int          nSel[4];      // 0->NQ, 1->ctrl->R, 2->ctrl->Dn
  int          splitk;
  int          applyInvn;
  const Ctrl*  ctrl;
};

__global__ __launch_bounds__(256)
void gemm_batched(GemmArgs ga){
  int batch = blockIdx.z / ga.splitk;
  int s     = blockIdx.z % ga.splitk;
  int n = decn(ga.nSel[batch], ga.ctrl);
  int qBase = blockIdx.x * BQ;
  if (qBase >= n) return;
  int wBase = blockIdx.y * BW;
  int kLen  = DIM / ga.splitk;
  int kStart = s * kLen;

  __shared__ float As[BK][BQ+PADQ];
  __shared__ float Bs[BK][BW+PADW];

  const float* feat  = ga.feat[batch];
  const float* proto = ga.proto[batch];
  const int*   idxl  = ga.idx[batch];

  int tid = threadIdx.x;
  int qr = tid & 127;
  int arow = qBase + qr;
  int garow = idxl ? idxl[min(arow, n-1)] : min(arow, n-1);
  const float* pA = feat + (size_t)garow*DIM + kStart;
  int akk0 = tid >> 7;              // 0..1

  int wr = tid & 63;
  int gbrow = wBase + wr;
  bool bok = (gbrow < WAYS);
  const float* pB = proto + (size_t)gbrow*DIM + kStart;
  int bkk0 = tid >> 6;              // 0..3

  int tx = tid & 15;                // w: tx*4
  int ty = tid >> 4;                // q: ty*8
  float acc[8][4];
#pragma unroll
  for (int i = 0; i < 8; i++)
#pragma unroll
    for (int j = 0; j < 4; j++) acc[i][j] = 0.f;

  float4 av[4], bv[2];
#pragma unroll
  for (int i = 0; i < 4; i++) av[i] = *(const float4*)(pA + (akk0 + 2*i)*4);
#pragma unroll
  for (int i = 0; i < 2; i++)
    bv[i] = bok ? *(const float4*)(pB + (bkk0 + 4*i)*4) : make_float4(0.f,0.f,0.f,0.f);

  for (int k0 = 0; k0 < kLen; k0 += BK){
    __syncthreads();
#pragma unroll
    for (int i = 0; i < 4; i++){
      int kk = (akk0 + 2*i)*4;
      As[kk+0][qr] = av[i].x; As[kk+1][qr] = av[i].y;
      As[kk+2][qr] = av[i].z; As[kk+3][qr] = av[i].w;
    }
#pragma unroll
    for (int i = 0; i < 2; i++){
      int kk = (bkk0 + 4*i)*4;
      Bs[kk+0][wr] = bv[i].x; Bs[kk+1][wr] = bv[i].y;
      Bs[kk+2][wr] = bv[i].z; Bs[kk+3][wr] = bv[i].w;
    }
    __syncthreads();
    int k1 = k0 + BK;
    bool more = (k1 < kLen);
    if (more){   // prefetch next tile during compute
#pragma unroll
      for (int i = 0; i < 4; i++) av[i] = *(const float4*)(pA + k1 + (akk0 + 2*i)*4);
#pragma unroll
      for (int i = 0; i < 2; i++)
        bv[i] = bok ? *(const float4*)(pB + k1 + (bkk0 + 4*i)*4) : make_float4(0.f,0.f,0.f,0.f);
    }
#pragma unroll
    for (int kk2 = 0; kk2 < BK; kk2++){
      float4 a0 = *(const float4*)&As[kk2][ty*8];
      float4 a1 = *(const float4*)&As[kk2][ty*8+4];
      float4 b0 = *(const float4*)&Bs[kk2][tx*4];
      float a8[8] = {a0.x,a0.y,a0.z,a0.w,a1.x,a1.y,a1.z,a1.w};
      float b4[4] = {b0.x,b0.y,b0.z,b0.w};
#pragma unroll
      for (int i = 0; i < 8; i++)
#pragma unroll
        for (int j = 0; j < 4; j++)
          acc[i][j] += a8[i]*b4[j];
    }
  }
  float* outBase = ga.outP[batch] + (size_t)s*NQ*WAYS;
  int wc = wBase + tx*4;
#pragma unroll
  for (int i = 0; i < 8; i++){
    int q = qBase + ty*8 + i;
    if (q >= n) continue;
    float scr = 1.f;
    if (ga.applyInvn){
      int gq = idxl ? idxl[q] : q;
      scr = ga.invn[batch][gq];
    }
    float* dst = outBase + (size_t)q*WAYS + wc;
    if (wc + 3 < WAYS){
      *(float4*)dst = make_float4(acc[i][0]*scr, acc[i][1]*scr, acc[i][2]*scr, acc[i][3]*scr);
    } else {
#pragma unroll
      for (int j = 0; j < 4; j++) if (wc + j < WAYS) dst[j] = acc[i][j]*scr;
    }
  }
}

// ---- combine K-slices, apply invn, colSq (batched, full-size only) ---------
struct CombArgs {
  const float* P;
  const float* invn[2];
  float* Ltgt[2];
  double* colSq;        // + b*WAYS
  int splitk;
};
__global__ __launch_bounds__(256)
void combine_batched(CombArgs ca){
  int b = blockIdx.y;
  int qBase = blockIdx.x * CQ;
  int t = threadIdx.x;
  int j = t % 25, r = t / 25;
  const float* Pb = ca.P + (size_t)b*ca.splitk*NQ*WAYS;
  const float* invn = ca.invn[b];
  float* L = ca.Ltgt[b];
  double sq0=0.0, sq1=0.0, sq2=0.0, sq3=0.0;
  if (r < 10){
    for (int i = r; i < CQ; i += 10){
      int q = qBase + i;
      if (q >= NQ) break;
      float sc = invn[q];
      const float* p0 = Pb + (size_t)q*WAYS + 4*j;
      float4 v = *(const float4*)p0;
      for (int s2 = 1; s2 < ca.splitk; s2++){
        float4 u = *(const float4*)(p0 + (size_t)s2*NQ*WAYS);
        v.x += u.x; v.y += u.y; v.z += u.z; v.w += u.w;
      }
      v.x *= sc; v.y *= sc; v.z *= sc; v.w *= sc;
      *(float4*)(L + (size_t)q*WAYS + 4*j) = v;
      sq0 += (double)v.x*(double)v.x;
      sq1 += (double)v.y*(double)v.y;
      sq2 += (double)v.z*(double)v.z;
      sq3 += (double)v.w*(double)v.w;
    }
  }
  __shared__ double red[WAYS][10];
  if (r < 10){
    red[4*j+0][r]=sq0; red[4*j+1][r]=sq1; red[4*j+2][r]=sq2; red[4*j+3][r]=sq3;
  }
  __syncthreads();
  if (t < WAYS){
    double s2 = 0.0;
#pragma unroll
    for (int rr = 0; rr < 10; rr++) s2 += red[t][rr];
    atomicAdd(ca.colSq + (size_t)b*WAYS + t, s2);
  }
}

// ---- column stats over (optionally indexed) rows: colSq + optional min/max -
struct StatArgs {
  const float* Lsrc[4];
  const int*   idx[4];
  int nSel[4];
  double* colSq;          // + b*WAYS
  unsigned* maxK;         // null -> skip minmax
  unsigned* negK;
  const Ctrl* ctrl;
};
__global__ __launch_bounds__(256)
void stats_batched(StatArgs sa){
  int b = blockIdx.y;
  int n = decn(sa.nSel[b], sa.ctrl);
  int qBase = blockIdx.x * CQ;
  if (qBase >= n) return;
  int t = threadIdx.x;
  int j = t % 25, r = t / 25;
  double sq0=0.0, sq1=0.0, sq2=0.0, sq3=0.0;
  float mx0=-3.4e38f,mx1=-3.4e38f,mx2=-3.4e38f,mx3=-3.4e38f;
  float mn0= 3.4e38f,mn1= 3.4e38f,mn2= 3.4e38f,mn3= 3.4e38f;
  if (r < 10){
    const int* idx = sa.idx[b];
    const float* L = sa.Lsrc[b];
    for (int i = r; i < CQ; i += 10){
      int q = qBase + i;
      if (q >= n) break;
      int gq = idx ? idx[q] : q;
      float4 v = *(const float4*)(L + (size_t)gq*WAYS + 4*j);
      sq0 += (double)v.x*(double)v.x; sq1 += (double)v.y*(double)v.y;
      sq2 += (double)v.z*(double)v.z; sq3 += (double)v.w*(double)v.w;
      mx0=fmaxf(mx0,v.x); mx1=fmaxf(mx1,v.y); mx2=fmaxf(mx2,v.z); mx3=fmaxf(mx3,v.w);
      mn0=fminf(mn0,v.x); mn1=fminf(mn1,v.y); mn2=fminf(mn2,v.z); mn3=fminf(mn3,v.w);
    }
  }
  __shared__ double red[WAYS][10];
  if (r < 10){
    red[4*j+0][r]=sq0; red[4*j+1][r]=sq1; red[4*j+2][r]=sq2; red[4*j+3][r]=sq3;
  }
  __syncthreads();
  if (t < WAYS){
    double s2 = 0.0;
#pragma unroll
    for (int rr = 0; rr < 10; rr++) s2 += red[t][rr];
    atomicAdd(sa.colSq + (size_t)b*WAYS + t, s2);
  }
  if (sa.maxK){
    __shared__ float redMx[WAYS][10], redMn[WAYS][10];
    if (r < 10){
      redMx[4*j+0][r]=mx0; redMx[4*j+1][r]=mx1; redMx[4*j+2][r]=mx2; redMx[4*j+3][r]=mx3;
      redMn[4*j+0][r]=mn0; redMn[4*j+1][r]=mn1; redMn[4*j+2][r]=mn2; redMn[4*j+3][r]=mn3;
    }
    __syncthreads();
    if (t < WAYS){
      float mx = -3.4e38f, mn = 3.4e38f;
#pragma unroll
      for (int rr = 0; rr < 10; rr++){ mx = fmaxf(mx, redMx[t][rr]); mn = fminf(mn, redMn[t][rr]); }
      atomicMax(sa.maxK + (size_t)b*WAYS + t, monokey(mx));
      atomicMax(sa.negK + (size_t)b*WAYS + t, monokey(-mn));
    }
  }
}

// ---- per-row max/argmax with lazy scale (batched, optional row index) ------
struct RS1Args {
  const float* Lsrc[4];
  const int*   idx[4];
  int nSel[4];
  const double* colSq;   // + b*WAYS
  const float* tpP;
  const Ctrl* ctrl;
  float* absCert; unsigned* keys; int* pseudo;   // + b*NQ
};
__global__ __launch_bounds__(256)
void rowstats1_b(RS1Args a){
  int b = blockIdx.y;
  int n = decn(a.nSel[b], a.ctrl);
  __shared__ float sc[WAYS];
  int t = threadIdx.x;
  if (t < WAYS) sc[t] = (*a.tpP) / ((float)sqrt(a.colSq[(size_t)b*WAYS+t]) + 1e-6f);
  __syncthreads();
  int q = blockIdx.x*256 + t;
  if (q >= n) return;
  int gq = a.idx[b] ? a.idx[b][q] : q;
  const float* row = a.Lsrc[b] + (size_t)gq*WAYS;
  float m = row[0]*sc[0]; int am = 0;
  for (int w = 1; w < WAYS; w++){
    float v = row[w]*sc[w];
    if (v > m){ m = v; am = w; }
  }
  a.absCert[(size_t)b*NQ+q] = m;
  a.pseudo [(size_t)b*NQ+q] = am;
  a.keys   [(size_t)b*NQ+q] = monokey(m);
}

// ---- per-row max + negative entropy (full, batched) ------------------------
struct RS2Args {
  const float* Lsrc[2];
  const double* colSq;   // + b*WAYS
  const float* tpP;
  float* absC; float* relC;   // + b*NQ
};
__global__ __launch_bounds__(256)
void rowstats2_b(RS2Args a){
  int b = blockIdx.y;
  __shared__ float sc[WAYS];
  int t = threadIdx.x;
  if (t < WAYS) sc[t] = (*a.tpP) / ((float)sqrt(a.colSq[(size_t)b*WAYS+t]) + 1e-6f);
  __syncthreads();
  int q = blockIdx.x*256 + t;
  if (q >= NQ) return;
  const float* row = a.Lsrc[b] + (size_t)q*WAYS;
  float m = row[0]*sc[0];
  for (int w = 1; w < WAYS; w++) m = fmaxf(m, row[w]*sc[w]);
  float s = 0.f;
  for (int w = 0; w < WAYS; w++) s += expf(row[w]*sc[w] - m);
  float inv = 1.0f / s, rel = 0.f;
  for (int w = 0; w < WAYS; w++){
    float p = expf(row[w]*sc[w] - m) * inv;
    rel += p * logf(p + 1e-10f);
  }
  a.absC[(size_t)b*NQ+q] = m;
  a.relC[(size_t)b*NQ+q] = rel;
}

// ---- fused radix-select + deterministic stable gather (batched) ------------
struct SGArgs {
  const unsigned* keys; const float* absCert;   // + b*NQ
  int nSel[4]; int instBase;
  int* selIdx; float* selVal;                    // + b*KSEL
  Ctrl* ctrl;
};
__global__ __launch_bounds__(1024)
void selectgather_b(SGArgs a){
  int b = blockIdx.x;
  int inst = a.instBase + b;
  int n = decn(a.nSel[b], a.ctrl);
  int k = n < KSEL ? n : KSEL;
  const unsigned* keys = a.keys + (size_t)b*NQ;
  const float* absCert = a.absCert + (size_t)b*NQ;
  int* selIdx = a.selIdx + b*KSEL;
  float* selVal = a.selVal + b*KSEL;
  __shared__ int hist[256];
  __shared__ unsigned sprefix;
  __shared__ int srem;
  int t = threadIdx.x;
  if (t == 0){ sprefix = 0u; srem = k; }
  __syncthreads();
  int nv4 = n >> 2;
  for (int pass = 0; pass < 4; pass++){
    int shift = 24 - 8*pass;
    if (t < 256) hist[t] = 0;
    __syncthreads();
    unsigned pref = sprefix;
    unsigned mask = (pass == 0) ? 0u : (0xFFFFFFFFu << (shift + 8));
    for (int i = t; i < nv4; i += 1024){
      uint4 kv = ((const uint4*)keys)[i];
      if ((kv.x & mask) == pref) atomicAdd(&hist[(kv.x >> shift) & 255], 1);
      if ((kv.y & mask) == pref) atomicAdd(&hist[(kv.y >> shift) & 255], 1);
      if ((kv.z & mask) == pref) atomicAdd(&hist[(kv.z >> shift) & 255], 1);
      if ((kv.w & mask) == pref) atomicAdd(&hist[(kv.w >> shift) & 255], 1);
    }
    for (int i = 4*nv4 + t; i < n; i += 1024){
      unsigned key = keys[i];
      if ((key & mask) == pref) atomicAdd(&hist[(key >> shift) & 255], 1);
    }
    __syncthreads();
    if (t == 0){
      int acc = 0, rem = srem, sel = 0;
      for (int b2 = 255; b2 >= 0; b2--){
        int h = hist[b2];
        if (acc + h >= rem){ sel = b2; srem = rem - acc; break; }
        acc += h;
      }
      sprefix = pref | ((unsigned)sel << shift);
    }
    __syncthreads();
  }
  unsigned T = sprefix;
  int rem = srem;
  if (t == 0){ a.ctrl->T[inst] = T; a.ctrl->rem[inst] = rem; a.ctrl->kk[inst] = k; }
  int cntGT = k - rem;
  const int CH = 10;
  int q0 = t*CH;
  int fg[CH], fe[CH]; int cg = 0, ce = 0;
  for (int i = 0; i < CH; i++){
    int q = q0 + i; int g = 0, e = 0;
    if (q < n){ unsigned key = keys[q]; g = key > T; e = (key == T); }
    fg[i] = g; fe[i] = e; cg += g; ce += e;
  }
  __shared__ int sG[1024], sE[1024];
  sG[t] = cg; sE[t] = ce; __syncthreads();
  for (int s = 1; s < 1024; s <<= 1){
    int vg = t >= s ? sG[t-s] : 0;
    int ve = t >= s ? sE[t-s] : 0;
    __syncthreads();
    sG[t] += vg; sE[t] += ve;
    __syncthreads();
  }
  int posG = sG[t] - cg, posE = sE[t] - ce;
  for (int i = 0; i < CH; i++){
    int q = q0 + i;
    if (q >= n) break;
    if (fg[i]){ selIdx[posG] = q; selVal[posG] = absCert[q]; posG++; }
    else if (fe[i]){
      if (posE < rem){ selIdx[cntGT+posE] = q; selVal[cntGT+posE] = absCert[q]; }
      posE++;
    }
  }
}

// ---- deterministic proto refine (batched) ----------------------------------
struct RefArgs {
  const float* feat[4]; const int* idx[4];
  const float* invn[4]; const float* proto[4];
  const int* selIdx; const float* selVal;   // + b*KSEL
  const int* pseudo;                        // + b*NQ
  float* protoRef;                          // + b*WAYS*DIM
  int instBase;
  const Ctrl* ctrl;
};
__global__ __launch_bounds__(256)
void refine_b(RefArgs a){
  int b = blockIdx.y;
  int w = blockIdx.x;
  int k = a.ctrl->kk[a.instBase + b];
  const int* selIdx = a.selIdx + b*KSEL;
  const float* selVal = a.selVal + b*KSEL;
  const int* pseudo = a.pseudo + (size_t)b*NQ;
  const int* idxl = a.idx[b];
  __shared__ int   sRow[KSEL];
  __shared__ float sCoef[KSEL];
  int t = threadIdx.x;
  for (int j = t; j < k; j += 256){
    int srow = selIdx[j];
    int grow = idxl ? idxl[srow] : srow;
    sRow[j]  = (pseudo[srow] == w) ? grow : -1;
    sCoef[j] = selVal[j] * a.invn[b][grow] / (float)k;
  }
  __syncthreads();
  float4 acc0 = make_float4(0.f,0.f,0.f,0.f);
  float4 acc1 = make_float4(0.f,0.f,0.f,0.f);
  int d0 = t*4, d1 = t*4 + 1024;
  const float* feat = a.feat[b];
  for (int j = 0; j < k; j++){
    int grow = sRow[j];
    if (grow < 0) continue;
    float c = sCoef[j];
    const float* fr = feat + (size_t)grow*DIM;
    float4 f0 = *(const float4*)(fr + d0);
    float4 f1 = *(const float4*)(fr + d1);
    acc0.x += c*f0.x; acc0.y += c*f0.y; acc0.z += c*f0.z; acc0.w += c*f0.w;
    acc1.x += c*f1.x; acc1.y += c*f1.y; acc1.z += c*f1.z; acc1.w += c*f1.w;
  }
  const float* pw = a.proto[b] + (size_t)w*DIM;
  float* pr = a.protoRef + ((size_t)b*WAYS + w)*DIM;
  float4 p0 = *(const float4*)(pw + d0);
  float4 p1 = *(const float4*)(pw + d1);
  *(float4*)(pr + d0) = make_float4(p0.x+acc0.x, p0.y+acc0.y, p0.z+acc0.z, p0.w+acc0.w);
  *(float4*)(pr + d1) = make_float4(p1.x+acc1.x, p1.y+acc1.y, p1.z+acc1.z, p1.w+acc1.w);
}

// ---- diff sign partition + index + w_r/w_f outputs -------------------------
__global__ __launch_bounds__(1024)
void diff_partition(const float* __restrict__ absC, const float* __restrict__ relC,
                    Ctrl* ctrl, int* __restrict__ resIdx, int* __restrict__ dctIdx,
                    float* __restrict__ out){
  const float* absCx = absC;        const float* absCd = absC + NQ;
  const float* relCx = relC;        const float* relCd = relC + NQ;
  const int CH = 10;
  int t = threadIdx.x, q0 = t*CH;
  int fr[CH], fd[CH]; int cr = 0, cd = 0;
  for (int i = 0; i < CH; i++){
    int q = q0 + i; int r = 0, dn = 0;
    if (q < NQ){
      float dv = absCx[q] - absCd[q] + relCx[q] - relCd[q];
      r = dv > 0.f; dn = dv < 0.f;
    }
    fr[i] = r; fd[i] = dn; cr += r; cd += dn;
  }
  __shared__ int sR[1024], sD[1024];
  sR[t] = cr; sD[t] = cd; __syncthreads();
  for (int s = 1; s < 1024; s <<= 1){
    int vr = t >= s ? sR[t-s] : 0;
    int vd = t >= s ? sD[t-s] : 0;
    __syncthreads();
    sR[t] += vr; sD[t] += vd;
    __syncthreads();
  }
  int R = sR[1023], Dn = sD[1023];
  int posR = sR[t] - cr, posD = sD[t] - cd;
  if (t == 0){ ctrl->R = R; ctrl->Dn = Dn; }
  for (int i = 0; i < CH; i++){
    int q = q0 + i;
    if (q >= NQ) break;
    if (fr[i]){ resIdx[posR] = q; out[2+posR] = (float)q; posR++; }
    if (fd[i]){ dctIdx[posD] = q; out[2+R+posD] = (float)q; posD++; }
  }
  for (int q = t; q < NQ; q += 1024){
    float a = absCx[q], b = absCd[q];
    float den = fmaxf(a + b, 1e-8f);
    out[2+R+Dn+q]      = a / den;
    out[2+R+Dn+NQ+q]   = b / den;
  }
}

// ---- per-way sum of exp(v*sc - m) (row-major, batched) ---------------------
struct SEArgs {
  const float* Lsrc[4];
  int nSel[4];
  const double* colSq;       // + b*WAYS  (second-pass subset slots)
  const unsigned* maxK; const unsigned* negK;
  double* sumExp;            // + b*WAYS
  const float* tpP;
  const Ctrl* ctrl;
};
__global__ __launch_bounds__(256)
void sumexp_batched(SEArgs a){
  int b = blockIdx.y;
  int n = decn(a.nSel[b], a.ctrl);
  int t = threadIdx.x;
  __shared__ float sc[WAYS], mv[WAYS];
  if (t < WAYS){
    float s = (*a.tpP) / ((float)sqrt(a.colSq[(size_t)b*WAYS+t]) + 1e-6f);
    float mxv = dekey(a.maxK[(size_t)b*WAYS+t]);
    float mnv = -dekey(a.negK[(size_t)b*WAYS+t]);
    sc[t] = s; mv[t] = (s >= 0.f) ? s*mxv : s*mnv;
  }
  __syncthreads();
  int qBase = blockIdx.x * CQ;
  if (qBase >= n) return;
  int j = t % 25, r = t / 25;
  double e0=0.0,e1=0.0,e2=0.0,e3=0.0;
  if (r < 10){
    const float* L = a.Lsrc[b];
    float s0=sc[4*j+0], s1=sc[4*j+1], s2=sc[4*j+2], s3=sc[4*j+3];
    float m0=mv[4*j+0], m1=mv[4*j+1], m2=mv[4*j+2], m3=mv[4*j+3];
    for (int i = r; i < CQ; i += 10){
      int q = qBase + i;
      if (q >= n) break;
      float4 v = *(const float4*)(L + (size_t)q*WAYS + 4*j);
      e0 += (double)expf(v.x*s0 - m0);
      e1 += (double)expf(v.y*s1 - m1);
      e2 += (double)expf(v.z*s2 - m2);
      e3 += (double)expf(v.w*s3 - m3);
    }
  }
  __shared__ double red[WAYS][10];
  if (r < 10){
    red[4*j+0][r]=e0; red[4*j+1][r]=e1; red[4*j+2][r]=e2; red[4*j+3][r]=e3;
  }
  __syncthreads();
  if (t < WAYS){
    double s2 = 0.0;
#pragma unroll
    for (int rr = 0; rr < 10; rr++) s2 += red[t][rr];
    atomicAdd(a.sumExp + (size_t)b*WAYS + t, s2);
  }
}

// ---- KL sum (two pairs batched) --------------------------------------------
struct KLArgs {
  const float* bufs[4];
  const double* colSq2;      // + b*WAYS (second-pass subset slots)
  const unsigned* maxK; const unsigned* negK; const double* sumExp;
  const float* tpP;
  Ctrl* ctrl;
};
__global__ __launch_bounds__(256)
void klsum_batched(KLArgs a){
  int p = blockIdx.y;
  int bL = p ? 3 : 1, bH = p ? 2 : 0;
  int n = p ? a.ctrl->Dn : a.ctrl->R;
  __shared__ float scL[WAYS], lseL[WAYS], scH[WAYS], lseH[WAYS];
  int t = threadIdx.x;
  if (t < WAYS){
    float tp = *a.tpP;
    {
      float s = tp / ((float)sqrt(a.colSq2[(size_t)bL*WAYS+t]) + 1e-6f);
      float mxv = dekey(a.maxK[(size_t)bL*WAYS+t]);
      float mnv = -dekey(a.negK[(size_t)bL*WAYS+t]);
      float m = (s >= 0.f) ? s*mxv : s*mnv;
      scL[t] = s; lseL[t] = m + (float)log(a.sumExp[(size_t)bL*WAYS+t]);
    }
    {
      float s = tp / ((float)sqrt(a.colSq2[(size_t)bH*WAYS+t]) + 1e-6f);
      float mxv = dekey(a.maxK[(size_t)bH*WAYS+t]);
      float mnv = -dekey(a.negK[(size_t)bH*WAYS+t]);
      float m = (s >= 0.f) ? s*mxv : s*mnv;
      scH[t] = s; lseH[t] = m + (float)log(a.sumExp[(size_t)bH*WAYS+t]);
    }
  }
  __syncthreads();
  const float* Lm = a.bufs[bL];
  const float* Hm = a.bufs[bH];
  size_t total = (size_t)n * WAYS;
  double loc = 0.0;
  for (size_t i = (size_t)blockIdx.x*256 + t; i < total; i += (size_t)gridDim.x*256){
    int w = (int)(i % WAYS);
    float lh = Hm[i]*scH[w] - lseH[w];
    float ll = Lm[i]*scL[w] - lseL[w];
    loc += (double)(expf(lh) * (lh - ll));
  }
  __shared__ double sd[256];
  sd[t] = loc; __syncthreads();
  for (int st = 128; st > 0; st >>= 1){
    if (t < st) sd[t] += sd[t + st];
    __syncthreads();
  }
  if (t == 0) atomicAdd(&a.ctrl->klsum[p], sd[0]);
}

// ---- weight sums (both losses batched) -------------------------------------
__global__ __launch_bounds__(256)
void wsum_b(const float* __restrict__ absC, const int* __restrict__ resIdx,
            const int* __restrict__ dctIdx, Ctrl* ctrl){
  int b = blockIdx.y;
  int n = b ? ctrl->Dn : ctrl->R;
  const float* src = b ? (absC + NQ) : absC;
  const int* idx = b ? dctIdx : resIdx;
  double loc = 0.0;
  for (int i = blockIdx.x*256 + threadIdx.x; i < n; i += gridDim.x*256)
    loc += (double)src[idx[i]];
  __shared__ double sd[256];
  sd[threadIdx.x] = loc; __syncthreads();
  for (int st = 128; st > 0; st >>= 1){
    if (threadIdx.x < st) sd[threadIdx.x] += sd[threadIdx.x + st];
    __syncthreads();
  }
  if (threadIdx.x == 0) atomicAdd(&ctrl->wsum[b], sd[0]);
  if (blockIdx.x == 0 && threadIdx.x == 0 && n > 0) ctrl->w0[b] = src[idx[0]];
}

__global__ void final_kernel(const Ctrl* ctrl, const float* tP, const float* tdP,
                             float* out){
  if (threadIdx.x == 0 && blockIdx.x == 0){
    float lossd = ctrl->w0[0] * (float)ctrl->klsum[0] / ((float)ctrl->wsum[0] + 1e-8f);
    float lossr = ctrl->w0[1] * (float)ctrl->klsum[1] / ((float)ctrl->wsum[1] + 1e-8f);
    out[0] = (*tP)  * lossr;
    out[1] = (*tdP) * lossd;
  }
}

extern "C" void kernel_launch(void* const* d_in, const int* in_sizes, int n_in,
                              void* d_out, int out_size, void* d_ws, size_t ws_size,
                              hipStream_t stream)
{
  const float* xs  = (const float*)d_in[0];
  const float* xq  = (const float*)d_in[1];
  const float* dsh = (const float*)d_in[2];
  const float* dq  = (const float*)d_in[3];
  const float* tpP = (const float*)d_in[4];
  const float* tP  = (const float*)d_in[5];
  const float* tdP = (const float*)d_in[6];
  float* out = (float*)d_out;

  char* base = (char*)d_ws;
  Ctrl* ctrl = (Ctrl*)base;
  double*   colSqAll = (double*)(base + 512);                   // 12 x WAYS
  unsigned* maxK     = (unsigned*)(base + 512 + 9600);          // 4 x WAYS
  unsigned* negK     = maxK + 4*WAYS;                           // 4 x WAYS
  double*   sumExp   = (double*)(base + 512 + 9600 + 3200);     // 4 x WAYS
  size_t zone = 512 + 9600 + 3200 + 3200;                       // 16512 B
  size_t off = (zone + 255) & ~(size_t)255;
  auto alloc = [&](size_t nElem)->void*{ void* p = base + off; off += nElem*4; return p; };
  float* protoX   = (float*)alloc((size_t)WAYS*DIM);
  float* protoD   = (float*)alloc((size_t)WAYS*DIM);
  float* protoRef = (float*)alloc((size_t)6*WAYS*DIM);   // 0,1 full; 2..5 subset
  float* invnX    = (float*)alloc(NQ);
  float* invnD    = (float*)alloc(NQ);
  float* Lx0      = (float*)alloc((size_t)NQ*WAYS);      // full first-pass L (X)
  float* Ld0      = (float*)alloc((size_t)NQ*WAYS);      // full first-pass L (D)
  float* bufs     = (float*)alloc((size_t)4*NQ*WAYS);    // subset final L; [0,1] alias LxF/LdF
  float* absCertF = (float*)alloc((size_t)2*NQ);
  unsigned* keysF = (unsigned*)alloc((size_t)2*NQ);
  int*   pseudoF  = (int*)alloc((size_t)2*NQ);
  float* absCertS = (float*)alloc((size_t)4*NQ);
  unsigned* keysS = (unsigned*)alloc((size_t)4*NQ);
  int*   pseudoS  = (int*)alloc((size_t)4*NQ);
  float* absC     = (float*)alloc((size_t)2*NQ);
  float* relC     = (float*)alloc((size_t)2*NQ);
  int*   selIdx   = (int*)alloc((size_t)4*KSEL);
  float* selVal   = (float*)alloc((size_t)4*KSEL);
  int*   resIdx   = (int*)alloc(NQ);
  int*   dctIdx   = (int*)alloc(NQ);
  if (off > ws_size) return;
  float* LxF = bufs;                        // full second-pass L (consumed before bufs written)
  float* LdF = bufs + (size_t)NQ*WAYS;

  float* P = (float*)(base + off);
  int splitkF;
  if      (off + (size_t)8*NQ*WAYS*4 <= ws_size) splitkF = 4;
  else if (off + (size_t)4*NQ*WAYS*4 <= ws_size) splitkF = 2;
  else splitkF = 1;

  hipMemsetAsync(base, 0, zone, stream);
  proto_kernel<<<2*WAYS, 256, 0, stream>>>(xs, dsh, protoX, protoD);
  invnorm_kernel<<<(2*NQ+3)/4, 256, 0, stream>>>(xq, dq, invnX, invnD);

  dim3 gFull(( NQ + BQ - 1)/BQ, (WAYS + BW - 1)/BW, 2*splitkF);
  int sgrid = (NQ + CQ - 1)/CQ;

  // ---------------- full phase, pass 1 ----------------
  GemmArgs g1{};
  g1.feat[0]=xq; g1.feat[1]=dq;
  g1.proto[0]=protoX; g1.proto[1]=protoD;
  g1.nSel[0]=0; g1.nSel[1]=0;
  g1.splitk=splitkF; g1.ctrl=ctrl;
  if (splitkF > 1){
    g1.outP[0]=P; g1.outP[1]=P + (size_t)splitkF*NQ*WAYS; g1.applyInvn=0;
  } else {
    g1.outP[0]=Lx0; g1.outP[1]=Ld0; g1.applyInvn=1;
    g1.invn[0]=invnX; g1.invn[1]=invnD;
  }
  gemm_batched<<<gFull,256,0,stream>>>(g1);
  if (splitkF > 1){
    CombArgs c1{}; c1.P=P; c1.invn[0]=invnX; c1.invn[1]=invnD;
    c1.Ltgt[0]=Lx0; c1.Ltgt[1]=Ld0; c1.colSq=colSqAll; c1.splitk=splitkF;
    combine_batched<<<dim3(sgrid,2),256,0,stream>>>(c1);
  } else {
    StatArgs s1{}; s1.Lsrc[0]=Lx0; s1.Lsrc[1]=Ld0;
    s1.nSel[0]=0; s1.nSel[1]=0; s1.colSq=colSqAll; s1.ctrl=ctrl;
    stats_batched<<<dim3(sgrid,2),256,0,stream>>>(s1);
  }
  RS1Args r1{}; r1.Lsrc[0]=Lx0; r1.Lsrc[1]=Ld0;
  r1.nSel[0]=0; r1.nSel[1]=0; r1.colSq=colSqAll; r1.tpP=tpP; r1.ctrl=ctrl;
  r1.absCert=absCertF; r1.keys=keysF; r1.pseudo=pseudoF;
  rowstats1_b<<<dim3((NQ+255)/256,2),256,0,stream>>>(r1);
  SGArgs sg1{}; sg1.keys=keysF; sg1.absCert=absCertF;
  sg1.nSel[0]=0; sg1.nSel[1]=0; sg1.instBase=0;
  sg1.selIdx=selIdx; sg1.selVal=selVal; sg1.ctrl=ctrl;
  selectgather_b<<<2,1024,0,stream>>>(sg1);
  RefArgs rf1{}; rf1.feat[0]=xq; rf1.feat[1]=dq;
  rf1.invn[0]=invnX; rf1.invn[1]=invnD;
  rf1.proto[0]=protoX; rf1.proto[1]=protoD;
  rf1.selIdx=selIdx; rf1.selVal=selVal; rf1.pseudo=pseudoF;
  rf1.protoRef=protoRef; rf1.instBase=0; rf1.ctrl=ctrl;
  refine_b<<<dim3(WAYS,2),256,0,stream>>>(rf1);

  // ---------------- full phase, pass 2 ----------------
  GemmArgs g2 = g1;
  g2.proto[0]=protoRef; g2.proto[1]=protoRef + (size_t)WAYS*DIM;
  if (splitkF == 1){ g2.outP[0]=LxF; g2.outP[1]=LdF; }
  gemm_batched<<<gFull,256,0,stream>>>(g2);
  if (splitkF > 1){
    CombArgs c2{}; c2.P=P; c2.invn[0]=invnX; c2.invn[1]=invnD;
    c2.Ltgt[0]=LxF; c2.Ltgt[1]=LdF; c2.colSq=colSqAll + 2*WAYS; c2.splitk=splitkF;
    combine_batched<<<dim3(sgrid,2),256,0,stream>>>(c2);
  } else {
    StatArgs s2{}; s2.Lsrc[0]=LxF; s2.Lsrc[1]=LdF;
    s2.nSel[0]=0; s2.nSel[1]=0; s2.colSq=colSqAll + 2*WAYS; s2.ctrl=ctrl;
    stats_batched<<<dim3(sgrid,2),256,0,stream>>>(s2);
  }
  RS2Args r2{}; r2.Lsrc[0]=LxF; r2.Lsrc[1]=LdF;
  r2.colSq=colSqAll + 2*WAYS; r2.tpP=tpP; r2.absC=absC; r2.relC=relC;
  rowstats2_b<<<dim3((NQ+255)/256,2),256,0,stream>>>(r2);

  diff_partition<<<1,1024,0,stream>>>(absC, relC, ctrl, resIdx, dctIdx, out);

  // ---------------- subset phase (batch of 4: lrh, ldl, ldh, lrl) ----------
  // b0: x/res  b1: d/res  b2: d/dct  b3: x/dct
  StatArgs ss1{};
  ss1.Lsrc[0]=Lx0; ss1.Lsrc[1]=Ld0; ss1.Lsrc[2]=Ld0; ss1.Lsrc[3]=Lx0;
  ss1.idx[0]=resIdx; ss1.idx[1]=resIdx; ss1.idx[2]=dctIdx; ss1.idx[3]=dctIdx;
  ss1.nSel[0]=1; ss1.nSel[1]=1; ss1.nSel[2]=2; ss1.nSel[3]=2;
  ss1.colSq=colSqAll + 4*WAYS; ss1.ctrl=ctrl;
  stats_batched<<<dim3(sgrid,4),256,0,stream>>>(ss1);
  RS1Args rs{}; rs.Lsrc[0]=Lx0; rs.Lsrc[1]=Ld0; rs.Lsrc[2]=Ld0; rs.Lsrc[3]=Lx0;
  rs.idx[0]=resIdx; rs.idx[1]=resIdx; rs.idx[2]=dctIdx; rs.idx[3]=dctIdx;
  rs.nSel[0]=1; rs.nSel[1]=1; rs.nSel[2]=2; rs.nSel[3]=2;
  rs.colSq=colSqAll + 4*WAYS; rs.tpP=tpP; rs.ctrl=ctrl;
  rs.absCert=absCertS; rs.keys=keysS; rs.pseudo=pseudoS;
  rowstats1_b<<<dim3((NQ+255)/256,4),256,0,stream>>>(rs);
  SGArgs sg2{}; sg2.keys=keysS; sg2.absCert=absCertS;
  sg2.nSel[0]=1; sg2.nSel[1]=1; sg2.nSel[2]=2; sg2.nSel[3]=2; sg2.instBase=2;
  sg2.selIdx=selIdx; sg2.selVal=selVal; sg2.ctrl=ctrl;
  selectgather_b<<<4,1024,0,stream>>>(sg2);
  RefArgs rf2{};
  rf2.feat[0]=xq; rf2.feat[1]=dq; rf2.feat[2]=dq; rf2.feat[3]=xq;
  rf2.idx[0]=resIdx; rf2.idx[1]=resIdx; rf2.idx[2]=dctIdx; rf2.idx[3]=dctIdx;
  rf2.invn[0]=invnX; rf2.invn[1]=invnD; rf2.invn[2]=invnD; rf2.invn[3]=invnX;
  rf2.proto[0]=protoX; rf2.proto[1]=protoD; rf2.proto[2]=protoD; rf2.proto[3]=protoX;
  rf2.selIdx=selIdx; rf2.selVal=selVal; rf2.pseudo=pseudoS;
  rf2.protoRef=protoRef + (size_t)2*WAYS*DIM; rf2.instBase=2; rf2.ctrl=ctrl;
  refine_b<<<dim3(WAYS,4),256,0,stream>>>(rf2);
  GemmArgs gs{};
  gs.feat[0]=xq; gs.feat[1]=dq; gs.feat[2]=dq; gs.feat[3]=xq;
  for (int b = 0; b < 4; b++){
    gs.proto[b] = protoRef + (size_t)(2+b)*WAYS*DIM;
    gs.outP[b]  = bufs + (size_t)b*NQ*WAYS;
  }
  gs.idx[0]=resIdx; gs.idx[1]=resIdx; gs.idx[2]=dctIdx; gs.idx[3]=dctIdx;
  gs.invn[0]=invnX; gs.invn[1]=invnD; gs.invn[2]=invnD; gs.invn[3]=invnX;
  gs.nSel[0]=1; gs.nSel[1]=1; gs.nSel[2]=2; gs.nSel[3]=2;
  gs.splitk=1; gs.applyInvn=1; gs.ctrl=ctrl;
  gemm_batched<<<dim3((NQ+BQ-1)/BQ,(WAYS+BW-1)/BW,4),256,0,stream>>>(gs);
  StatArgs ss2{};
  for (int b = 0; b < 4; b++) ss2.Lsrc[b] = bufs + (size_t)b*NQ*WAYS;
  ss2.nSel[0]=1; ss2.nSel[1]=1; ss2.nSel[2]=2; ss2.nSel[3]=2;
  ss2.colSq=colSqAll + 8*WAYS; ss2.maxK=maxK; ss2.negK=negK; ss2.ctrl=ctrl;
  stats_batched<<<dim3(sgrid,4),256,0,stream>>>(ss2);
  SEArgs se{};
  for (int b = 0; b < 4; b++) se.Lsrc[b] = bufs + (size_t)b*NQ*WAYS;
  se.nSel[0]=1; se.nSel[1]=1; se.nSel[2]=2; se.nSel[3]=2;
  se.colSq=colSqAll + 8*WAYS; se.maxK=maxK; se.negK=negK;
  se.sumExp=sumExp; se.tpP=tpP; se.ctrl=ctrl;
  sumexp_batched<<<dim3(sgrid,4),256,0,stream>>>(se);
  KLArgs kl{};
  for (int b = 0; b < 4; b++) kl.bufs[b] = bufs + (size_t)b*NQ*WAYS;
  kl.colSq2=colSqAll + 8*WAYS; kl.maxK=maxK; kl.negK=negK; kl.sumExp=sumExp;
  kl.tpP=tpP; kl.ctrl=ctrl;
  klsum_batched<<<dim3(64,2),256,0,stream>>>(kl);
  wsum_b<<<dim3((NQ+255)/256,2),256,0,stream>>>(absC, resIdx, dctIdx, ctrl);
  final_kernel<<<1,64,0,stream>>>(ctrl, tP, tdP, out);
}